// Round 1
// baseline (5161.422 us; speedup 1.0000x reference)
//
#include <hip/hip_runtime.h>

#define NN 50000
#define EE 800000
#define D 128
#define NCLS 3
#define MIDX 10000

// h[node, f] = sum_k x[node,k] * W[f,k] + b[f]
__global__ void linear128(const float* __restrict__ x, const float* __restrict__ W,
                          const float* __restrict__ b, float* __restrict__ h) {
    __shared__ float xs[D];
    const int node = blockIdx.x;
    const int t = threadIdx.x;
    xs[t] = x[node * D + t];
    __syncthreads();
    const float* wrow = W + t * D;
    float acc = b[t];
#pragma unroll 8
    for (int k = 0; k < D; ++k) acc = fmaf(xs[k], wrow[k], acc);
    h[node * D + t] = acc;
}

// one thread per (edge, 4-feature chunk): 32 chunks per edge
__global__ void scatter_add(const float* __restrict__ h, const int* __restrict__ src,
                            const int* __restrict__ dst, float* __restrict__ agg) {
    const long long idx = (long long)blockIdx.x * blockDim.x + threadIdx.x;
    if (idx >= (long long)EE * 32) return;
    const int e = (int)(idx >> 5);
    const int c = (int)(idx & 31) << 2;
    const int s = src[e];
    const int d = dst[e];
    const float4 v = *(const float4*)(h + (long long)s * D + c);
    float* p = agg + (long long)d * D + c;
    atomicAdd(p + 0, v.x);
    atomicAdd(p + 1, v.y);
    atomicAdd(p + 2, v.z);
    atomicAdd(p + 3, v.w);
}

// out = relu(agg + h)   (leaky_relu after relu is identity)
__global__ void relu_add(const float* __restrict__ agg, const float* __restrict__ h,
                         float* __restrict__ out) {
    const int i = blockIdx.x * blockDim.x + threadIdx.x;
    if (i >= NN * D / 4) return;
    const float4 a = ((const float4*)agg)[i];
    const float4 b = ((const float4*)h)[i];
    float4 r;
    r.x = fmaxf(a.x + b.x, 0.f);
    r.y = fmaxf(a.y + b.y, 0.f);
    r.z = fmaxf(a.z + b.z, 0.f);
    r.w = fmaxf(a.w + b.w, 0.f);
    ((float4*)out)[i] = r;
}

// logits = x @ Wout^T + bout; ypred = argmax (first-max tie rule, as float)
__global__ void head(const float* __restrict__ x, const float* __restrict__ Wout,
                     const float* __restrict__ bout, float* __restrict__ logits,
                     float* __restrict__ ypred) {
    const int n = blockIdx.x * blockDim.x + threadIdx.x;
    if (n >= NN) return;
    const float4* xr = (const float4*)(x + (long long)n * D);
    float acc0 = bout[0], acc1 = bout[1], acc2 = bout[2];
    const float4* w0 = (const float4*)(Wout + 0 * D);
    const float4* w1 = (const float4*)(Wout + 1 * D);
    const float4* w2 = (const float4*)(Wout + 2 * D);
#pragma unroll 8
    for (int k = 0; k < D / 4; ++k) {
        const float4 v = xr[k];
        float4 w;
        w = w0[k]; acc0 += v.x * w.x + v.y * w.y + v.z * w.z + v.w * w.w;
        w = w1[k]; acc1 += v.x * w.x + v.y * w.y + v.z * w.z + v.w * w.w;
        w = w2[k]; acc2 += v.x * w.x + v.y * w.y + v.z * w.z + v.w * w.w;
    }
    logits[n * 3 + 0] = acc0;
    logits[n * 3 + 1] = acc1;
    logits[n * 3 + 2] = acc2;
    int best = 0;
    float bv = acc0;
    if (acc1 > bv) { bv = acc1; best = 1; }
    if (acc2 > bv) { bv = acc2; best = 2; }
    ypred[n] = (float)best;
}

__global__ void gather_out(const float* __restrict__ logits, const float* __restrict__ ypred,
                           const int* __restrict__ nidx, float* __restrict__ node_out,
                           float* __restrict__ y_nodepred) {
    const int m = blockIdx.x * blockDim.x + threadIdx.x;
    if (m >= MIDX) return;
    const int n = nidx[m];
    node_out[m * 3 + 0] = logits[n * 3 + 0];
    node_out[m * 3 + 1] = logits[n * 3 + 1];
    node_out[m * 3 + 2] = logits[n * 3 + 2];
    y_nodepred[m] = ypred[n];
}

extern "C" void kernel_launch(void* const* d_in, const int* in_sizes, int n_in,
                              void* d_out, int out_size, void* d_ws, size_t ws_size,
                              hipStream_t stream) {
    const float* x0 = (const float*)d_in[0];
    const int* ei = (const int*)d_in[1];
    const int* src = ei;             // edge_index[0]
    const int* dst = ei + EE;        // edge_index[1]
    // d_in[2] = node_label (unused by reference)
    const int* nidx = (const int*)d_in[3];
    const float* W1 = (const float*)d_in[4];
    const float* b1 = (const float*)d_in[5];
    const float* W2 = (const float*)d_in[6];
    const float* b2 = (const float*)d_in[7];
    const float* W3 = (const float*)d_in[8];
    const float* b3 = (const float*)d_in[9];
    const float* Wout = (const float*)d_in[10];
    const float* bout = (const float*)d_in[11];

    float* ws = (float*)d_ws;
    float* hbuf   = ws;                       // N*D
    float* agg    = ws + (long long)NN * D;   // N*D
    float* xbuf   = ws + 2LL * NN * D;        // N*D
    float* logits = ws + 3LL * NN * D;        // N*3

    float* out = (float*)d_out;
    float* xe        = out;                        // N*D
    float* node_out  = out + (long long)NN * D;    // M*3
    float* yp        = node_out + MIDX * NCLS;     // N
    float* ynp       = yp + NN;                    // M

    const int scatter_threads = 256;
    const long long scatter_total = (long long)EE * 32;
    const int scatter_blocks = (int)((scatter_total + scatter_threads - 1) / scatter_threads);
    const int ra_blocks = (NN * D / 4 + 255) / 256;

    auto layer = [&](const float* xin, const float* W, const float* b, float* xout) {
        linear128<<<NN, D, 0, stream>>>(xin, W, b, hbuf);
        hipMemsetAsync(agg, 0, (size_t)NN * D * sizeof(float), stream);
        scatter_add<<<scatter_blocks, scatter_threads, 0, stream>>>(hbuf, src, dst, agg);
        relu_add<<<ra_blocks, 256, 0, stream>>>(agg, hbuf, xout);
    };

    layer(x0, W1, b1, xbuf);
    layer(xbuf, W2, b2, xbuf);   // xbuf only read by linear128, safe to overwrite after
    layer(xbuf, W3, b3, xe);

    head<<<(NN + 255) / 256, 256, 0, stream>>>(xe, Wout, bout, logits, yp);
    gather_out<<<(MIDX + 255) / 256, 256, 0, stream>>>(logits, yp, nidx, node_out, ynp);
}

// Round 2
// 521.775 us; speedup vs baseline: 9.8920x; 9.8920x over previous
//
#include <hip/hip_runtime.h>

#define NN 50000
#define EE 800000
#define D 128
#define NCLS 3
#define MIDX 10000
#define NPB 16  // nodes per block in linear (50000 = 16 * 3125, exact)

// ---- CSR build ----------------------------------------------------------

__global__ void hist_kernel(const int* __restrict__ dst, int* __restrict__ counts) {
    const int e = blockIdx.x * blockDim.x + threadIdx.x;
    if (e < EE) atomicAdd(&counts[dst[e]], 1);
}

// single block, 256 threads: exclusive scan of counts -> rowptr (+ cursor copy)
__global__ void build_rowptr(const int* __restrict__ counts, int* __restrict__ rowptr,
                             int* __restrict__ cursor) {
    __shared__ int sums[256];
    const int t = threadIdx.x;
    const int C = (NN + 255) / 256;  // 196
    const int lo = t * C;
    const int hi = (lo + C < NN) ? lo + C : NN;
    int s = 0;
    for (int i = lo; i < hi; ++i) s += counts[i];
    sums[t] = s;
    __syncthreads();
    for (int off = 1; off < 256; off <<= 1) {
        const int add = (t >= off) ? sums[t - off] : 0;
        __syncthreads();
        sums[t] += add;
        __syncthreads();
    }
    int run = sums[t] - s;  // exclusive prefix of this thread's segment
    for (int i = lo; i < hi; ++i) {
        rowptr[i] = run;
        cursor[i] = run;
        run += counts[i];
    }
    if (t == 255) rowptr[NN] = run;  // == EE
}

__global__ void fill_kernel(const int* __restrict__ src, const int* __restrict__ dst,
                            int* __restrict__ cursor, int* __restrict__ esrc) {
    const int e = blockIdx.x * blockDim.x + threadIdx.x;
    if (e < EE) {
        const int p = atomicAdd(&cursor[dst[e]], 1);
        esrc[p] = src[e];
    }
}

// ---- compute ------------------------------------------------------------

// h[node, f] = sum_k x[node,k] * W[f,k] + b[f]; 16 nodes per block for W reuse
__global__ __launch_bounds__(128) void linear128v2(const float* __restrict__ x,
                                                   const float* __restrict__ W,
                                                   const float* __restrict__ b,
                                                   float* __restrict__ h) {
    __shared__ float4 xs[NPB][D / 4];  // 8 KB
    const int t = threadIdx.x;
    const long long base = (long long)blockIdx.x * NPB;
    {
        const float4* xv = (const float4*)(x + base * D);
        float4* s = &xs[0][0];
#pragma unroll
        for (int i = 0; i < NPB * D / 4 / 128; ++i)  // 4
            s[t + i * 128] = xv[t + i * 128];
    }
    __syncthreads();
    float acc[NPB];
    const float bb = b[t];
#pragma unroll
    for (int j = 0; j < NPB; ++j) acc[j] = bb;
    const float4* wrow = (const float4*)(W + t * D);
#pragma unroll 4
    for (int k4 = 0; k4 < D / 4; ++k4) {
        const float4 w = wrow[k4];
#pragma unroll
        for (int j = 0; j < NPB; ++j) {
            const float4 v = xs[j][k4];
            acc[j] = fmaf(v.x, w.x, acc[j]);
            acc[j] = fmaf(v.y, w.y, acc[j]);
            acc[j] = fmaf(v.z, w.z, acc[j]);
            acc[j] = fmaf(v.w, w.w, acc[j]);
        }
    }
    float* hp = h + base * D + t;
#pragma unroll
    for (int j = 0; j < NPB; ++j) hp[(long long)j * D] = acc[j];
}

// out[n] = relu( sum_{s in nbrs(n)} h[s] + h[n] )   (leaky_relu folded away)
__global__ __launch_bounds__(128) void gin_aggregate(const float* __restrict__ h,
                                                     const int* __restrict__ rowptr,
                                                     const int* __restrict__ esrc,
                                                     float* __restrict__ out) {
    const int node = blockIdx.x;
    const int t = threadIdx.x;
    const int beg = rowptr[node];
    const int end = rowptr[node + 1];
    float acc = h[(long long)node * D + t];
    int i = beg;
    for (; i + 4 <= end; i += 4) {
        const int s0 = esrc[i], s1 = esrc[i + 1], s2 = esrc[i + 2], s3 = esrc[i + 3];
        const float v0 = h[(long long)s0 * D + t];
        const float v1 = h[(long long)s1 * D + t];
        const float v2 = h[(long long)s2 * D + t];
        const float v3 = h[(long long)s3 * D + t];
        acc += (v0 + v1) + (v2 + v3);
    }
    for (; i < end; ++i) acc += h[(long long)esrc[i] * D + t];
    out[(long long)node * D + t] = fmaxf(acc, 0.f);
}

__global__ void head(const float* __restrict__ x, const float* __restrict__ Wout,
                     const float* __restrict__ bout, float* __restrict__ logits,
                     float* __restrict__ ypred) {
    const int n = blockIdx.x * blockDim.x + threadIdx.x;
    if (n >= NN) return;
    const float4* xr = (const float4*)(x + (long long)n * D);
    float acc0 = bout[0], acc1 = bout[1], acc2 = bout[2];
    const float4* w0 = (const float4*)(Wout + 0 * D);
    const float4* w1 = (const float4*)(Wout + 1 * D);
    const float4* w2 = (const float4*)(Wout + 2 * D);
#pragma unroll 8
    for (int k = 0; k < D / 4; ++k) {
        const float4 v = xr[k];
        float4 w;
        w = w0[k]; acc0 += v.x * w.x + v.y * w.y + v.z * w.z + v.w * w.w;
        w = w1[k]; acc1 += v.x * w.x + v.y * w.y + v.z * w.z + v.w * w.w;
        w = w2[k]; acc2 += v.x * w.x + v.y * w.y + v.z * w.z + v.w * w.w;
    }
    logits[n * 3 + 0] = acc0;
    logits[n * 3 + 1] = acc1;
    logits[n * 3 + 2] = acc2;
    int best = 0;
    float bv = acc0;
    if (acc1 > bv) { bv = acc1; best = 1; }
    if (acc2 > bv) { bv = acc2; best = 2; }
    ypred[n] = (float)best;
}

__global__ void gather_out(const float* __restrict__ logits, const float* __restrict__ ypred,
                           const int* __restrict__ nidx, float* __restrict__ node_out,
                           float* __restrict__ y_nodepred) {
    const int m = blockIdx.x * blockDim.x + threadIdx.x;
    if (m >= MIDX) return;
    const int n = nidx[m];
    node_out[m * 3 + 0] = logits[n * 3 + 0];
    node_out[m * 3 + 1] = logits[n * 3 + 1];
    node_out[m * 3 + 2] = logits[n * 3 + 2];
    y_nodepred[m] = ypred[n];
}

extern "C" void kernel_launch(void* const* d_in, const int* in_sizes, int n_in,
                              void* d_out, int out_size, void* d_ws, size_t ws_size,
                              hipStream_t stream) {
    const float* x0 = (const float*)d_in[0];
    const int* ei = (const int*)d_in[1];
    const int* src = ei;        // edge_index[0]
    const int* dst = ei + EE;   // edge_index[1]
    const int* nidx = (const int*)d_in[3];
    const float* W1 = (const float*)d_in[4];
    const float* b1 = (const float*)d_in[5];
    const float* W2 = (const float*)d_in[6];
    const float* b2 = (const float*)d_in[7];
    const float* W3 = (const float*)d_in[8];
    const float* b3 = (const float*)d_in[9];
    const float* Wout = (const float*)d_in[10];
    const float* bout = (const float*)d_in[11];

    char* ws = (char*)d_ws;
    float* hbuf   = (float*)ws;                                   // N*D
    float* xbuf   = hbuf + (long long)NN * D;                     // N*D
    float* logits = xbuf + (long long)NN * D;                     // N*3
    int* counts   = (int*)(logits + (long long)NN * NCLS);        // NN+1
    int* cursor   = counts + (NN + 1);                            // NN
    int* esrc     = cursor + NN;                                  // EE
    int* rowptr   = esrc + EE;                                    // NN+1

    float* out = (float*)d_out;
    float* xe       = out;                       // N*D
    float* node_out = out + (long long)NN * D;   // M*3
    float* yp       = node_out + MIDX * NCLS;    // N
    float* ynp      = yp + NN;                   // M

    // ---- CSR build (per call; no cross-call state) ----
    hipMemsetAsync(counts, 0, (NN + 1) * sizeof(int), stream);
    hist_kernel<<<(EE + 255) / 256, 256, 0, stream>>>(dst, counts);
    build_rowptr<<<1, 256, 0, stream>>>(counts, rowptr, cursor);
    fill_kernel<<<(EE + 255) / 256, 256, 0, stream>>>(src, dst, cursor, esrc);

    // ---- 3 GIN layers ----
    auto layer = [&](const float* xin, const float* W, const float* b, float* xout) {
        linear128v2<<<NN / NPB, 128, 0, stream>>>(xin, W, b, hbuf);
        gin_aggregate<<<NN, 128, 0, stream>>>(hbuf, rowptr, esrc, xout);
    };
    layer(x0, W1, b1, xbuf);
    layer(xbuf, W2, b2, xbuf);  // aggregate reads only hbuf; safe overwrite
    layer(xbuf, W3, b3, xe);

    head<<<(NN + 255) / 256, 256, 0, stream>>>(xe, Wout, bout, logits, yp);
    gather_out<<<(MIDX + 255) / 256, 256, 0, stream>>>(logits, yp, nidx, node_out, ynp);
}

// Round 3
// 402.898 us; speedup vs baseline: 12.8108x; 1.2951x over previous
//
#include <hip/hip_runtime.h>

#define NN 50000
#define EE 800000
#define D 128
#define NCLS 3
#define MIDX 10000
#define NPB 16           // nodes per block in linear
#define SCAN_B 196       // ceil(50000/256)

// ---- CSR build ----------------------------------------------------------

__global__ void hist_kernel(const int* __restrict__ dst, int* __restrict__ counts) {
    const int e = blockIdx.x * blockDim.x + threadIdx.x;
    if (e < EE) atomicAdd(&counts[dst[e]], 1);
}

// phase 1: per-block sums of counts
__global__ void scan_bsum(const int* __restrict__ counts, int* __restrict__ bsums) {
    __shared__ int s[256];
    const int t = threadIdx.x;
    const int i = blockIdx.x * 256 + t;
    s[t] = (i < NN) ? counts[i] : 0;
    __syncthreads();
    for (int off = 128; off > 0; off >>= 1) {
        if (t < off) s[t] += s[t + off];
        __syncthreads();
    }
    if (t == 0) bsums[blockIdx.x] = s[0];
}

// phase 2: single block exclusive-scans the 196 block sums
__global__ void scan_tops(const int* __restrict__ bsums, int* __restrict__ boffs) {
    __shared__ int s[256];
    const int t = threadIdx.x;
    const int v = (t < SCAN_B) ? bsums[t] : 0;
    s[t] = v;
    __syncthreads();
    for (int off = 1; off < 256; off <<= 1) {
        const int add = (t >= off) ? s[t - off] : 0;
        __syncthreads();
        s[t] += add;
        __syncthreads();
    }
    if (t < SCAN_B) boffs[t] = s[t] - v;  // exclusive
}

// phase 3: per-block scan + block offset -> rowptr & cursor
__global__ void scan_write(const int* __restrict__ counts, const int* __restrict__ boffs,
                           int* __restrict__ rowptr, int* __restrict__ cursor) {
    __shared__ int s[256];
    const int t = threadIdx.x;
    const int i = blockIdx.x * 256 + t;
    const int v = (i < NN) ? counts[i] : 0;
    s[t] = v;
    __syncthreads();
    for (int off = 1; off < 256; off <<= 1) {
        const int add = (t >= off) ? s[t - off] : 0;
        __syncthreads();
        s[t] += add;
        __syncthreads();
    }
    const int excl = boffs[blockIdx.x] + s[t] - v;
    if (i < NN) {
        rowptr[i] = excl;
        cursor[i] = excl;
        if (i == NN - 1) rowptr[NN] = excl + v;  // == EE
    }
}

__global__ void fill_kernel(const int* __restrict__ src, const int* __restrict__ dst,
                            int* __restrict__ cursor, int* __restrict__ esrc) {
    const int e = blockIdx.x * blockDim.x + threadIdx.x;
    if (e < EE) {
        const int p = atomicAdd(&cursor[dst[e]], 1);
        esrc[p] = src[e];
    }
}

// ---- compute ------------------------------------------------------------

__global__ __launch_bounds__(128) void linear128v2(const float* __restrict__ x,
                                                   const float* __restrict__ W,
                                                   const float* __restrict__ b,
                                                   float* __restrict__ h) {
    __shared__ float4 xs[NPB][D / 4];  // 8 KB
    const int t = threadIdx.x;
    const long long base = (long long)blockIdx.x * NPB;
    {
        const float4* xv = (const float4*)(x + base * D);
        float4* s = &xs[0][0];
#pragma unroll
        for (int i = 0; i < NPB * D / 4 / 128; ++i)  // 4
            s[t + i * 128] = xv[t + i * 128];
    }
    __syncthreads();
    float acc[NPB];
    const float bb = b[t];
#pragma unroll
    for (int j = 0; j < NPB; ++j) acc[j] = bb;
    const float4* wrow = (const float4*)(W + t * D);
#pragma unroll 4
    for (int k4 = 0; k4 < D / 4; ++k4) {
        const float4 w = wrow[k4];
#pragma unroll
        for (int j = 0; j < NPB; ++j) {
            const float4 v = xs[j][k4];
            acc[j] = fmaf(v.x, w.x, acc[j]);
            acc[j] = fmaf(v.y, w.y, acc[j]);
            acc[j] = fmaf(v.z, w.z, acc[j]);
            acc[j] = fmaf(v.w, w.w, acc[j]);
        }
    }
    float* hp = h + base * D + t;
#pragma unroll
    for (int j = 0; j < NPB; ++j) hp[(long long)j * D] = acc[j];
}

// out[n] = relu( sum_{s in nbrs(n)} h[s] + h[n] )
__global__ __launch_bounds__(128) void gin_aggregate(const float* __restrict__ h,
                                                     const int* __restrict__ rowptr,
                                                     const int* __restrict__ esrc,
                                                     float* __restrict__ out) {
    const int node = blockIdx.x;
    const int t = threadIdx.x;
    const int beg = rowptr[node];
    const int end = rowptr[node + 1];
    float acc = h[(long long)node * D + t];
    int i = beg;
    for (; i + 8 <= end; i += 8) {
        float v0 = h[(long long)esrc[i + 0] * D + t];
        float v1 = h[(long long)esrc[i + 1] * D + t];
        float v2 = h[(long long)esrc[i + 2] * D + t];
        float v3 = h[(long long)esrc[i + 3] * D + t];
        float v4 = h[(long long)esrc[i + 4] * D + t];
        float v5 = h[(long long)esrc[i + 5] * D + t];
        float v6 = h[(long long)esrc[i + 6] * D + t];
        float v7 = h[(long long)esrc[i + 7] * D + t];
        acc += ((v0 + v1) + (v2 + v3)) + ((v4 + v5) + (v6 + v7));
    }
    for (; i < end; ++i) acc += h[(long long)esrc[i] * D + t];
    out[(long long)node * D + t] = fmaxf(acc, 0.f);
}

__global__ void head(const float* __restrict__ x, const float* __restrict__ Wout,
                     const float* __restrict__ bout, float* __restrict__ logits,
                     float* __restrict__ ypred) {
    const int n = blockIdx.x * blockDim.x + threadIdx.x;
    if (n >= NN) return;
    const float4* xr = (const float4*)(x + (long long)n * D);
    float acc0 = bout[0], acc1 = bout[1], acc2 = bout[2];
    const float4* w0 = (const float4*)(Wout + 0 * D);
    const float4* w1 = (const float4*)(Wout + 1 * D);
    const float4* w2 = (const float4*)(Wout + 2 * D);
#pragma unroll 8
    for (int k = 0; k < D / 4; ++k) {
        const float4 v = xr[k];
        float4 w;
        w = w0[k]; acc0 += v.x * w.x + v.y * w.y + v.z * w.z + v.w * w.w;
        w = w1[k]; acc1 += v.x * w.x + v.y * w.y + v.z * w.z + v.w * w.w;
        w = w2[k]; acc2 += v.x * w.x + v.y * w.y + v.z * w.z + v.w * w.w;
    }
    logits[n * 3 + 0] = acc0;
    logits[n * 3 + 1] = acc1;
    logits[n * 3 + 2] = acc2;
    int best = 0;
    float bv = acc0;
    if (acc1 > bv) { bv = acc1; best = 1; }
    if (acc2 > bv) { bv = acc2; best = 2; }
    ypred[n] = (float)best;
}

__global__ void gather_out(const float* __restrict__ logits, const float* __restrict__ ypred,
                           const int* __restrict__ nidx, float* __restrict__ node_out,
                           float* __restrict__ y_nodepred) {
    const int m = blockIdx.x * blockDim.x + threadIdx.x;
    if (m >= MIDX) return;
    const int n = nidx[m];
    node_out[m * 3 + 0] = logits[n * 3 + 0];
    node_out[m * 3 + 1] = logits[n * 3 + 1];
    node_out[m * 3 + 2] = logits[n * 3 + 2];
    y_nodepred[m] = ypred[n];
}

extern "C" void kernel_launch(void* const* d_in, const int* in_sizes, int n_in,
                              void* d_out, int out_size, void* d_ws, size_t ws_size,
                              hipStream_t stream) {
    const float* x0 = (const float*)d_in[0];
    const int* ei = (const int*)d_in[1];
    const int* src = ei;        // edge_index[0]
    const int* dst = ei + EE;   // edge_index[1]
    const int* nidx = (const int*)d_in[3];
    const float* W1 = (const float*)d_in[4];
    const float* b1 = (const float*)d_in[5];
    const float* W2 = (const float*)d_in[6];
    const float* b2 = (const float*)d_in[7];
    const float* W3 = (const float*)d_in[8];
    const float* b3 = (const float*)d_in[9];
    const float* Wout = (const float*)d_in[10];
    const float* bout = (const float*)d_in[11];

    char* ws = (char*)d_ws;
    float* hbuf   = (float*)ws;                                   // N*D
    float* xbuf   = hbuf + (long long)NN * D;                     // N*D
    float* logits = xbuf + (long long)NN * D;                     // N*3
    int* counts   = (int*)(logits + (long long)NN * NCLS);        // NN+1
    int* cursor   = counts + (NN + 1);                            // NN
    int* esrc     = cursor + NN;                                  // EE
    int* rowptr   = esrc + EE;                                    // NN+1
    int* bsums    = rowptr + (NN + 1);                            // SCAN_B
    int* boffs    = bsums + SCAN_B;                               // SCAN_B

    float* out = (float*)d_out;
    float* xe       = out;                       // N*D
    float* node_out = out + (long long)NN * D;   // M*3
    float* yp       = node_out + MIDX * NCLS;    // N
    float* ynp      = yp + NN;                   // M

    // ---- CSR build ----
    hipMemsetAsync(counts, 0, (NN + 1) * sizeof(int), stream);
    hist_kernel<<<(EE + 255) / 256, 256, 0, stream>>>(dst, counts);
    scan_bsum<<<SCAN_B, 256, 0, stream>>>(counts, bsums);
    scan_tops<<<1, 256, 0, stream>>>(bsums, boffs);
    scan_write<<<SCAN_B, 256, 0, stream>>>(counts, boffs, rowptr, cursor);
    fill_kernel<<<(EE + 255) / 256, 256, 0, stream>>>(src, dst, cursor, esrc);

    // ---- 3 GIN layers ----
    auto layer = [&](const float* xin, const float* W, const float* b, float* xout) {
        linear128v2<<<NN / NPB, 128, 0, stream>>>(xin, W, b, hbuf);
        gin_aggregate<<<NN, 128, 0, stream>>>(hbuf, rowptr, esrc, xout);
    };
    layer(x0, W1, b1, xbuf);
    layer(xbuf, W2, b2, xbuf);
    layer(xbuf, W3, b3, xe);

    head<<<(NN + 255) / 256, 256, 0, stream>>>(xe, Wout, bout, logits, yp);
    gather_out<<<(MIDX + 255) / 256, 256, 0, stream>>>(logits, yp, nidx, node_out, ynp);
}

// Round 4
// 326.743 us; speedup vs baseline: 15.7966x; 1.2331x over previous
//
#include <hip/hip_runtime.h>

#define NN 50000
#define EE 800000
#define D 128
#define NCLS 3
#define MIDX 10000
#define NPB 16           // nodes per block in linear
#define SCAN_B 196       // ceil(50000/256)

typedef unsigned int uint32;
typedef unsigned short ushort16;

__device__ __forceinline__ ushort16 f2bf(float f) {
    uint32 u = __float_as_uint(f);
    u = (u + 0x7fffu + ((u >> 16) & 1u)) >> 16;  // round-to-nearest-even
    return (ushort16)u;
}
__device__ __forceinline__ float bflo(uint32 packed) {  // low ushort -> float
    return __uint_as_float(packed << 16);
}
__device__ __forceinline__ float bfhi(uint32 packed) {  // high ushort -> float
    return __uint_as_float(packed & 0xFFFF0000u);
}

// ---- CSR build ----------------------------------------------------------

__global__ void hist_kernel(const int* __restrict__ dst, int* __restrict__ counts) {
    const int e = blockIdx.x * blockDim.x + threadIdx.x;
    if (e < EE) atomicAdd(&counts[dst[e]], 1);
}

__global__ void scan_bsum(const int* __restrict__ counts, int* __restrict__ bsums) {
    __shared__ int s[256];
    const int t = threadIdx.x;
    const int i = blockIdx.x * 256 + t;
    s[t] = (i < NN) ? counts[i] : 0;
    __syncthreads();
    for (int off = 128; off > 0; off >>= 1) {
        if (t < off) s[t] += s[t + off];
        __syncthreads();
    }
    if (t == 0) bsums[blockIdx.x] = s[0];
}

__global__ void scan_tops(const int* __restrict__ bsums, int* __restrict__ boffs) {
    __shared__ int s[256];
    const int t = threadIdx.x;
    const int v = (t < SCAN_B) ? bsums[t] : 0;
    s[t] = v;
    __syncthreads();
    for (int off = 1; off < 256; off <<= 1) {
        const int add = (t >= off) ? s[t - off] : 0;
        __syncthreads();
        s[t] += add;
        __syncthreads();
    }
    if (t < SCAN_B) boffs[t] = s[t] - v;
}

__global__ void scan_write(const int* __restrict__ counts, const int* __restrict__ boffs,
                           int* __restrict__ rowptr, int* __restrict__ cursor) {
    __shared__ int s[256];
    const int t = threadIdx.x;
    const int i = blockIdx.x * 256 + t;
    const int v = (i < NN) ? counts[i] : 0;
    s[t] = v;
    __syncthreads();
    for (int off = 1; off < 256; off <<= 1) {
        const int add = (t >= off) ? s[t - off] : 0;
        __syncthreads();
        s[t] += add;
        __syncthreads();
    }
    const int excl = boffs[blockIdx.x] + s[t] - v;
    if (i < NN) {
        rowptr[i] = excl;
        cursor[i] = excl;
        if (i == NN - 1) rowptr[NN] = excl + v;
    }
}

__global__ void fill_kernel(const int* __restrict__ src, const int* __restrict__ dst,
                            int* __restrict__ cursor, int* __restrict__ esrc) {
    const int e = blockIdx.x * blockDim.x + threadIdx.x;
    if (e < EE) {
        const int p = atomicAdd(&cursor[dst[e]], 1);
        esrc[p] = src[e];
    }
}

// ---- compute ------------------------------------------------------------

// fp32 x, fp32 W -> bf16 h
__global__ __launch_bounds__(128) void linear128_bf16out(const float* __restrict__ x,
                                                         const float* __restrict__ W,
                                                         const float* __restrict__ b,
                                                         ushort16* __restrict__ h) {
    __shared__ float4 xs[NPB][D / 4];
    const int t = threadIdx.x;
    const long long base = (long long)blockIdx.x * NPB;
    {
        const float4* xv = (const float4*)(x + base * D);
        float4* s = &xs[0][0];
#pragma unroll
        for (int i = 0; i < NPB * D / 4 / 128; ++i)
            s[t + i * 128] = xv[t + i * 128];
    }
    __syncthreads();
    float acc[NPB];
    const float bb = b[t];
#pragma unroll
    for (int j = 0; j < NPB; ++j) acc[j] = bb;
    const float4* wrow = (const float4*)(W + t * D);
#pragma unroll 4
    for (int k4 = 0; k4 < D / 4; ++k4) {
        const float4 w = wrow[k4];
#pragma unroll
        for (int j = 0; j < NPB; ++j) {
            const float4 v = xs[j][k4];
            acc[j] = fmaf(v.x, w.x, acc[j]);
            acc[j] = fmaf(v.y, w.y, acc[j]);
            acc[j] = fmaf(v.z, w.z, acc[j]);
            acc[j] = fmaf(v.w, w.w, acc[j]);
        }
    }
    ushort16* hp = h + base * D + t;
#pragma unroll
    for (int j = 0; j < NPB; ++j) hp[(long long)j * D] = f2bf(acc[j]);
}

// one WAVE per node; 64 lanes x ushort2 covers the 128-feature bf16 row.
// out[n] = relu( sum_{s in nbrs(n)} h[s] + h[n] )   in fp32
__global__ __launch_bounds__(256) void gin_aggregate_bf16(const uint32* __restrict__ h,
                                                          const int* __restrict__ rowptr,
                                                          const int* __restrict__ esrc,
                                                          float* __restrict__ out) {
    const int wave = threadIdx.x >> 6;
    const int lane = threadIdx.x & 63;
    const int node = __builtin_amdgcn_readfirstlane(blockIdx.x * 4 + wave);
    if (node >= NN) return;
    const int beg = rowptr[node];
    const int end = rowptr[node + 1];
    // self term
    uint32 p = h[(long long)node * (D / 2) + lane];
    float acc0 = bflo(p), acc1 = bfhi(p);
    int i = beg;
    for (; i + 8 <= end; i += 8) {
        const int s0 = esrc[i + 0], s1 = esrc[i + 1], s2 = esrc[i + 2], s3 = esrc[i + 3];
        const int s4 = esrc[i + 4], s5 = esrc[i + 5], s6 = esrc[i + 6], s7 = esrc[i + 7];
        const uint32 p0 = h[(long long)s0 * (D / 2) + lane];
        const uint32 p1 = h[(long long)s1 * (D / 2) + lane];
        const uint32 p2 = h[(long long)s2 * (D / 2) + lane];
        const uint32 p3 = h[(long long)s3 * (D / 2) + lane];
        const uint32 p4 = h[(long long)s4 * (D / 2) + lane];
        const uint32 p5 = h[(long long)s5 * (D / 2) + lane];
        const uint32 p6 = h[(long long)s6 * (D / 2) + lane];
        const uint32 p7 = h[(long long)s7 * (D / 2) + lane];
        acc0 += ((bflo(p0) + bflo(p1)) + (bflo(p2) + bflo(p3))) +
                ((bflo(p4) + bflo(p5)) + (bflo(p6) + bflo(p7)));
        acc1 += ((bfhi(p0) + bfhi(p1)) + (bfhi(p2) + bfhi(p3))) +
                ((bfhi(p4) + bfhi(p5)) + (bfhi(p6) + bfhi(p7)));
    }
    for (; i < end; ++i) {
        const uint32 q = h[(long long)esrc[i] * (D / 2) + lane];
        acc0 += bflo(q);
        acc1 += bfhi(q);
    }
    float2 r;
    r.x = fmaxf(acc0, 0.f);
    r.y = fmaxf(acc1, 0.f);
    ((float2*)(out + (long long)node * D))[lane] = r;
}

__global__ void head(const float* __restrict__ x, const float* __restrict__ Wout,
                     const float* __restrict__ bout, float* __restrict__ logits,
                     float* __restrict__ ypred) {
    const int n = blockIdx.x * blockDim.x + threadIdx.x;
    if (n >= NN) return;
    const float4* xr = (const float4*)(x + (long long)n * D);
    float acc0 = bout[0], acc1 = bout[1], acc2 = bout[2];
    const float4* w0 = (const float4*)(Wout + 0 * D);
    const float4* w1 = (const float4*)(Wout + 1 * D);
    const float4* w2 = (const float4*)(Wout + 2 * D);
#pragma unroll 8
    for (int k = 0; k < D / 4; ++k) {
        const float4 v = xr[k];
        float4 w;
        w = w0[k]; acc0 += v.x * w.x + v.y * w.y + v.z * w.z + v.w * w.w;
        w = w1[k]; acc1 += v.x * w.x + v.y * w.y + v.z * w.z + v.w * w.w;
        w = w2[k]; acc2 += v.x * w.x + v.y * w.y + v.z * w.z + v.w * w.w;
    }
    logits[n * 3 + 0] = acc0;
    logits[n * 3 + 1] = acc1;
    logits[n * 3 + 2] = acc2;
    int best = 0;
    float bv = acc0;
    if (acc1 > bv) { bv = acc1; best = 1; }
    if (acc2 > bv) { bv = acc2; best = 2; }
    ypred[n] = (float)best;
}

__global__ void gather_out(const float* __restrict__ logits, const float* __restrict__ ypred,
                           const int* __restrict__ nidx, float* __restrict__ node_out,
                           float* __restrict__ y_nodepred) {
    const int m = blockIdx.x * blockDim.x + threadIdx.x;
    if (m >= MIDX) return;
    const int n = nidx[m];
    node_out[m * 3 + 0] = logits[n * 3 + 0];
    node_out[m * 3 + 1] = logits[n * 3 + 1];
    node_out[m * 3 + 2] = logits[n * 3 + 2];
    y_nodepred[m] = ypred[n];
}

extern "C" void kernel_launch(void* const* d_in, const int* in_sizes, int n_in,
                              void* d_out, int out_size, void* d_ws, size_t ws_size,
                              hipStream_t stream) {
    const float* x0 = (const float*)d_in[0];
    const int* ei = (const int*)d_in[1];
    const int* src = ei;        // edge_index[0]
    const int* dst = ei + EE;   // edge_index[1]
    const int* nidx = (const int*)d_in[3];
    const float* W1 = (const float*)d_in[4];
    const float* b1 = (const float*)d_in[5];
    const float* W2 = (const float*)d_in[6];
    const float* b2 = (const float*)d_in[7];
    const float* W3 = (const float*)d_in[8];
    const float* b3 = (const float*)d_in[9];
    const float* Wout = (const float*)d_in[10];
    const float* bout = (const float*)d_in[11];

    char* ws = (char*)d_ws;
    ushort16* hbuf = (ushort16*)ws;                               // N*D bf16
    float* xbuf   = (float*)(ws + (long long)NN * D * 2);         // N*D f32
    float* logits = xbuf + (long long)NN * D;                     // N*3
    int* counts   = (int*)(logits + (long long)NN * NCLS);        // NN+1
    int* cursor   = counts + (NN + 1);                            // NN
    int* esrc     = cursor + NN;                                  // EE
    int* rowptr   = esrc + EE;                                    // NN+1
    int* bsums    = rowptr + (NN + 1);                            // SCAN_B
    int* boffs    = bsums + SCAN_B;                               // SCAN_B

    float* out = (float*)d_out;
    float* xe       = out;                       // N*D
    float* node_out = out + (long long)NN * D;   // M*3
    float* yp       = node_out + MIDX * NCLS;    // N
    float* ynp      = yp + NN;                   // M

    // ---- CSR build ----
    hipMemsetAsync(counts, 0, (NN + 1) * sizeof(int), stream);
    hist_kernel<<<(EE + 255) / 256, 256, 0, stream>>>(dst, counts);
    scan_bsum<<<SCAN_B, 256, 0, stream>>>(counts, bsums);
    scan_tops<<<1, 256, 0, stream>>>(bsums, boffs);
    scan_write<<<SCAN_B, 256, 0, stream>>>(counts, boffs, rowptr, cursor);
    fill_kernel<<<(EE + 255) / 256, 256, 0, stream>>>(src, dst, cursor, esrc);

    // ---- 3 GIN layers ----
    const int agg_blocks = (NN + 3) / 4;
    auto layer = [&](const float* xin, const float* W, const float* b, float* xout) {
        linear128_bf16out<<<NN / NPB, 128, 0, stream>>>(xin, W, b, hbuf);
        gin_aggregate_bf16<<<agg_blocks, 256, 0, stream>>>((const uint32*)hbuf, rowptr, esrc, xout);
    };
    layer(x0, W1, b1, xbuf);
    layer(xbuf, W2, b2, xbuf);
    layer(xbuf, W3, b3, xe);

    head<<<(NN + 255) / 256, 256, 0, stream>>>(xe, Wout, bout, logits, yp);
    gather_out<<<(MIDX + 255) / 256, 256, 0, stream>>>(logits, yp, nidx, node_out, ynp);
}

// Round 5
// 248.367 us; speedup vs baseline: 20.7814x; 1.3156x over previous
//
#include <hip/hip_runtime.h>

#define NN 50000
#define EE 800000
#define D 128
#define NCLS 3
#define MIDX 10000
#define NB 196           // coarse buckets = ceil(NN/256); also scan blocks
#define CHUNK 4096       // edges per WG in fill_coarse

typedef unsigned int uint32;
typedef unsigned short ushort16;
typedef __attribute__((ext_vector_type(8))) short short8;
typedef __attribute__((ext_vector_type(4))) float f32x4;

__device__ __forceinline__ ushort16 f2bf(float f) {
    uint32 u = __float_as_uint(f);
    u = (u + 0x7fffu + ((u >> 16) & 1u)) >> 16;  // round-to-nearest-even
    return (ushort16)u;
}
__device__ __forceinline__ float bflo(uint32 packed) {
    return __uint_as_float(packed << 16);
}
__device__ __forceinline__ float bfhi(uint32 packed) {
    return __uint_as_float(packed & 0xFFFF0000u);
}

// ---- weight pre-convert (fp32 -> bf16, 3x 128x128) ----------------------

__global__ void wconv(const float* __restrict__ W1, const float* __restrict__ W2,
                      const float* __restrict__ W3, ushort16* __restrict__ Wbf) {
    const int i = blockIdx.x * blockDim.x + threadIdx.x;
    if (i >= 3 * D * D) return;
    const int j = i & (D * D - 1);
    const int sel = i >> 14;
    const float* W = (sel == 0) ? W1 : (sel == 1) ? W2 : W3;
    Wbf[i] = f2bf(W[j]);
}

// ---- CSR build ----------------------------------------------------------

__global__ void hist_kernel(const int* __restrict__ dst, int* __restrict__ counts) {
    const int e = blockIdx.x * blockDim.x + threadIdx.x;
    if (e < EE) atomicAdd(&counts[dst[e]], 1);
}

__global__ void scan_bsum(const int* __restrict__ counts, int* __restrict__ bsums) {
    __shared__ int s[256];
    const int t = threadIdx.x;
    const int i = blockIdx.x * 256 + t;
    s[t] = (i < NN) ? counts[i] : 0;
    __syncthreads();
    for (int off = 128; off > 0; off >>= 1) {
        if (t < off) s[t] += s[t + off];
        __syncthreads();
    }
    if (t == 0) bsums[blockIdx.x] = s[0];
}

__global__ void scan_tops(const int* __restrict__ bsums, int* __restrict__ boffs) {
    __shared__ int s[256];
    const int t = threadIdx.x;
    const int v = (t < NB) ? bsums[t] : 0;
    s[t] = v;
    __syncthreads();
    for (int off = 1; off < 256; off <<= 1) {
        const int add = (t >= off) ? s[t - off] : 0;
        __syncthreads();
        s[t] += add;
        __syncthreads();
    }
    if (t < NB) boffs[t] = s[t] - v;
}

// rowptr + padded coarse-bucket cursors (one counter per 64B line)
__global__ void scan_write(const int* __restrict__ counts, const int* __restrict__ boffs,
                           int* __restrict__ rowptr, int* __restrict__ bcursor) {
    __shared__ int s[256];
    const int t = threadIdx.x;
    const int i = blockIdx.x * 256 + t;
    const int v = (i < NN) ? counts[i] : 0;
    s[t] = v;
    __syncthreads();
    for (int off = 1; off < 256; off <<= 1) {
        const int add = (t >= off) ? s[t - off] : 0;
        __syncthreads();
        s[t] += add;
        __syncthreads();
    }
    const int excl = boffs[blockIdx.x] + s[t] - v;
    if (i < NN) {
        rowptr[i] = excl;
        if ((i & 255) == 0) bcursor[(i >> 8) * 16] = excl;
        if (i == NN - 1) rowptr[NN] = excl + v;
    }
}

// pass 1 of fill: per-WG LDS hist over coarse buckets, reserve slabs, write packed
__global__ __launch_bounds__(256) void fill_coarse(const int* __restrict__ src,
                                                   const int* __restrict__ dst,
                                                   int* __restrict__ bcursor,
                                                   int* __restrict__ espacked) {
    __shared__ int hcnt[256];
    __shared__ int hbase[256];
    const int t = threadIdx.x;
    const int e0 = blockIdx.x * CHUNK;
    const int e1 = (e0 + CHUNK < EE) ? e0 + CHUNK : EE;
    hcnt[t] = 0;
    __syncthreads();
    for (int s = e0 + t; s < e1; s += 256) atomicAdd(&hcnt[dst[s] >> 8], 1);
    __syncthreads();
    if (t < NB) {
        const int c = hcnt[t];
        hbase[t] = c ? atomicAdd(&bcursor[t * 16], c) : 0;
    }
    hcnt[t] = 0;  // safe: only thread t touched hcnt[t] since last sync
    __syncthreads();
    for (int s = e0 + t; s < e1; s += 256) {
        const int d = dst[s];
        const int b = d >> 8;
        const int r = atomicAdd(&hcnt[b], 1);
        espacked[hbase[b] + r] = (src[s] << 8) | (d & 255);
    }
}

// pass 2: exact in-bucket scatter via LDS cursors (writes stay in a 16KB window)
__global__ __launch_bounds__(256) void bucket_scatter(const int* __restrict__ espacked,
                                                      const int* __restrict__ rowptr,
                                                      int* __restrict__ esrc) {
    __shared__ int cur[256];
    const int b = blockIdx.x;
    const int t = threadIdx.x;
    const int n0 = b * 256;
    const int nhi = (n0 + 256 < NN) ? n0 + 256 : NN;
    const int seg0 = rowptr[n0];
    const int seg1 = rowptr[nhi];
    if (n0 + t < NN) cur[t] = rowptr[n0 + t];
    __syncthreads();
    for (int s = seg0 + t; s < seg1; s += 256) {
        const int p = espacked[s];
        const int pos = atomicAdd(&cur[p & 255], 1);
        esrc[pos] = p >> 8;
    }
}

// ---- MFMA linear: h[n,f] = bf16( sum_k x[n,k]*W[f,k] + b[f] ) -----------
// one wave per 16 nodes; 8 n-tiles x 4 k-steps of mfma_f32_16x16x32_bf16

__global__ __launch_bounds__(256) void linear_mfma(const float* __restrict__ x,
                                                   const ushort16* __restrict__ Wbf,
                                                   const float* __restrict__ bias,
                                                   ushort16* __restrict__ h) {
    const int wave = threadIdx.x >> 6;
    const int lane = threadIdx.x & 63;
    const int m0 = blockIdx.x * 64 + wave * 16;
    if (m0 >= NN) return;
    const int lr = lane & 15;         // A row / B col / D col
    const int lk = (lane >> 4) * 8;   // k-octet base

    f32x4 acc[8] = {};
    for (int k4 = 0; k4 < 4; ++k4) {
        const int kb = k4 * 32 + lk;
        const float4* xp = (const float4*)(x + (long long)(m0 + lr) * D + kb);
        const float4 a0 = xp[0];
        const float4 a1 = xp[1];
        short8 af;
        af[0] = (short)f2bf(a0.x); af[1] = (short)f2bf(a0.y);
        af[2] = (short)f2bf(a0.z); af[3] = (short)f2bf(a0.w);
        af[4] = (short)f2bf(a1.x); af[5] = (short)f2bf(a1.y);
        af[6] = (short)f2bf(a1.z); af[7] = (short)f2bf(a1.w);
#pragma unroll
        for (int nt = 0; nt < 8; ++nt) {
            const short8 bfrag = *(const short8*)(Wbf + (nt * 16 + lr) * D + kb);
            acc[nt] = __builtin_amdgcn_mfma_f32_16x16x32_bf16(af, bfrag, acc[nt], 0, 0, 0);
        }
    }
    const int rbase = m0 + (lane >> 4) * 4;
#pragma unroll
    for (int nt = 0; nt < 8; ++nt) {
        const int f = nt * 16 + lr;
        const float bb = bias[f];
#pragma unroll
        for (int r = 0; r < 4; ++r)
            h[(long long)(rbase + r) * D + f] = f2bf(acc[nt][r] + bb);
    }
}

// ---- aggregate (+ optional fused head) ----------------------------------

template <int FUSE_HEAD>
__global__ __launch_bounds__(256) void gin_aggregate_bf16(const uint32* __restrict__ h,
                                                          const int* __restrict__ rowptr,
                                                          const int* __restrict__ esrc,
                                                          float* __restrict__ out,
                                                          const float* __restrict__ Wout,
                                                          const float* __restrict__ bout,
                                                          float* __restrict__ logits,
                                                          float* __restrict__ ypred) {
    const int wave = threadIdx.x >> 6;
    const int lane = threadIdx.x & 63;
    const int node = __builtin_amdgcn_readfirstlane(blockIdx.x * 4 + wave);
    if (node >= NN) return;
    const int beg = rowptr[node];
    const int end = rowptr[node + 1];
    uint32 p = h[(long long)node * (D / 2) + lane];
    float acc0 = bflo(p), acc1 = bfhi(p);
    int i = beg;
    for (; i + 8 <= end; i += 8) {
        const int s0 = esrc[i + 0], s1 = esrc[i + 1], s2 = esrc[i + 2], s3 = esrc[i + 3];
        const int s4 = esrc[i + 4], s5 = esrc[i + 5], s6 = esrc[i + 6], s7 = esrc[i + 7];
        const uint32 p0 = h[(long long)s0 * (D / 2) + lane];
        const uint32 p1 = h[(long long)s1 * (D / 2) + lane];
        const uint32 p2 = h[(long long)s2 * (D / 2) + lane];
        const uint32 p3 = h[(long long)s3 * (D / 2) + lane];
        const uint32 p4 = h[(long long)s4 * (D / 2) + lane];
        const uint32 p5 = h[(long long)s5 * (D / 2) + lane];
        const uint32 p6 = h[(long long)s6 * (D / 2) + lane];
        const uint32 p7 = h[(long long)s7 * (D / 2) + lane];
        acc0 += ((bflo(p0) + bflo(p1)) + (bflo(p2) + bflo(p3))) +
                ((bflo(p4) + bflo(p5)) + (bflo(p6) + bflo(p7)));
        acc1 += ((bfhi(p0) + bfhi(p1)) + (bfhi(p2) + bfhi(p3))) +
                ((bfhi(p4) + bfhi(p5)) + (bfhi(p6) + bfhi(p7)));
    }
    for (; i < end; ++i) {
        const uint32 q = h[(long long)esrc[i] * (D / 2) + lane];
        acc0 += bflo(q);
        acc1 += bfhi(q);
    }
    float2 r;
    r.x = fmaxf(acc0, 0.f);
    r.y = fmaxf(acc1, 0.f);
    ((float2*)(out + (long long)node * D))[lane] = r;

    if (FUSE_HEAD) {
        const float2 w0 = ((const float2*)(Wout + 0 * D))[lane];
        const float2 w1 = ((const float2*)(Wout + 1 * D))[lane];
        const float2 w2 = ((const float2*)(Wout + 2 * D))[lane];
        float l0 = r.x * w0.x + r.y * w0.y;
        float l1 = r.x * w1.x + r.y * w1.y;
        float l2 = r.x * w2.x + r.y * w2.y;
#pragma unroll
        for (int off = 32; off > 0; off >>= 1) {
            l0 += __shfl_xor(l0, off, 64);
            l1 += __shfl_xor(l1, off, 64);
            l2 += __shfl_xor(l2, off, 64);
        }
        if (lane == 0) {
            l0 += bout[0]; l1 += bout[1]; l2 += bout[2];
            logits[node * 3 + 0] = l0;
            logits[node * 3 + 1] = l1;
            logits[node * 3 + 2] = l2;
            int best = 0;
            float bv = l0;
            if (l1 > bv) { bv = l1; best = 1; }
            if (l2 > bv) { bv = l2; best = 2; }
            ypred[node] = (float)best;
        }
    }
}

__global__ void gather_out(const float* __restrict__ logits, const float* __restrict__ ypred,
                           const int* __restrict__ nidx, float* __restrict__ node_out,
                           float* __restrict__ y_nodepred) {
    const int m = blockIdx.x * blockDim.x + threadIdx.x;
    if (m >= MIDX) return;
    const int n = nidx[m];
    node_out[m * 3 + 0] = logits[n * 3 + 0];
    node_out[m * 3 + 1] = logits[n * 3 + 1];
    node_out[m * 3 + 2] = logits[n * 3 + 2];
    y_nodepred[m] = ypred[n];
}

extern "C" void kernel_launch(void* const* d_in, const int* in_sizes, int n_in,
                              void* d_out, int out_size, void* d_ws, size_t ws_size,
                              hipStream_t stream) {
    const float* x0 = (const float*)d_in[0];
    const int* ei = (const int*)d_in[1];
    const int* src = ei;        // edge_index[0]
    const int* dst = ei + EE;   // edge_index[1]
    const int* nidx = (const int*)d_in[3];
    const float* W1 = (const float*)d_in[4];
    const float* b1 = (const float*)d_in[5];
    const float* W2 = (const float*)d_in[6];
    const float* b2 = (const float*)d_in[7];
    const float* W3 = (const float*)d_in[8];
    const float* b3 = (const float*)d_in[9];
    const float* Wout = (const float*)d_in[10];
    const float* bout = (const float*)d_in[11];

    char* ws = (char*)d_ws;
    ushort16* hbuf = (ushort16*)ws;                                // N*D bf16
    float* xbuf    = (float*)(ws + (long long)NN * D * 2);         // N*D f32
    float* logits  = xbuf + (long long)NN * D;                     // N*3
    int* counts    = (int*)(logits + (long long)NN * NCLS);        // NN
    int* rowptr    = counts + NN;                                  // NN+4 (16B pad)
    int* bsums     = rowptr + NN + 4;                              // 256
    int* boffs     = bsums + 256;                                  // 256
    int* bcursor   = boffs + 256;                                  // NB*16 padded
    int* espacked  = bcursor + NB * 16 + 12;                       // EE (16B align)
    int* esrc      = espacked + EE;                                // EE
    ushort16* Wbf  = (ushort16*)(esrc + EE);                       // 3*D*D bf16

    float* out = (float*)d_out;
    float* xe       = out;                       // N*D
    float* node_out = out + (long long)NN * D;   // M*3
    float* yp       = node_out + MIDX * NCLS;    // N
    float* ynp      = yp + NN;                   // M

    // ---- weights -> bf16 ----
    wconv<<<(3 * D * D + 255) / 256, 256, 0, stream>>>(W1, W2, W3, Wbf);

    // ---- CSR build ----
    hipMemsetAsync(counts, 0, (size_t)NN * sizeof(int), stream);
    hist_kernel<<<(EE + 255) / 256, 256, 0, stream>>>(dst, counts);
    scan_bsum<<<NB, 256, 0, stream>>>(counts, bsums);
    scan_tops<<<1, 256, 0, stream>>>(bsums, boffs);
    scan_write<<<NB, 256, 0, stream>>>(counts, boffs, rowptr, bcursor);
    fill_coarse<<<(EE + CHUNK - 1) / CHUNK, 256, 0, stream>>>(src, dst, bcursor, espacked);
    bucket_scatter<<<NB, 256, 0, stream>>>(espacked, rowptr, esrc);

    // ---- 3 GIN layers ----
    const int lin_blocks = (NN + 63) / 64;
    const int agg_blocks = (NN + 3) / 4;
    linear_mfma<<<lin_blocks, 256, 0, stream>>>(x0, Wbf, b1, hbuf);
    gin_aggregate_bf16<0><<<agg_blocks, 256, 0, stream>>>((const uint32*)hbuf, rowptr, esrc,
                                                          xbuf, nullptr, nullptr, nullptr, nullptr);
    linear_mfma<<<lin_blocks, 256, 0, stream>>>(xbuf, Wbf + (long long)D * D, b2, hbuf);
    gin_aggregate_bf16<0><<<agg_blocks, 256, 0, stream>>>((const uint32*)hbuf, rowptr, esrc,
                                                          xbuf, nullptr, nullptr, nullptr, nullptr);
    linear_mfma<<<lin_blocks, 256, 0, stream>>>(xbuf, Wbf + 2LL * D * D, b3, hbuf);
    gin_aggregate_bf16<1><<<agg_blocks, 256, 0, stream>>>((const uint32*)hbuf, rowptr, esrc,
                                                          xe, Wout, bout, logits, yp);

    gather_out<<<(MIDX + 255) / 256, 256, 0, stream>>>(logits, yp, nidx, node_out, ynp);
}

// Round 6
// 225.961 us; speedup vs baseline: 22.8421x; 1.0992x over previous
//
#include <hip/hip_runtime.h>

#define NN 50000
#define EE 800000
#define D 128
#define NCLS 3
#define MIDX 10000
#define NB 196           // coarse buckets = ceil(NN/256)
#define CHUNK 4096       // edges per WG in fill_coarse

typedef unsigned int uint32;
typedef unsigned short ushort16;
typedef __attribute__((ext_vector_type(8))) short short8;
typedef __attribute__((ext_vector_type(4))) float f32x4;

__device__ __forceinline__ ushort16 f2bf(float f) {
    uint32 u = __float_as_uint(f);
    u = (u + 0x7fffu + ((u >> 16) & 1u)) >> 16;  // round-to-nearest-even
    return (ushort16)u;
}
__device__ __forceinline__ float bflo(uint32 packed) {
    return __uint_as_float(packed << 16);
}
__device__ __forceinline__ float bfhi(uint32 packed) {
    return __uint_as_float(packed & 0xFFFF0000u);
}

// ---- prep: x0 -> bf16, W1..3 -> bf16, zero gbucket -----------------------

__global__ void prep(const float* __restrict__ x0, const float* __restrict__ W1,
                     const float* __restrict__ W2, const float* __restrict__ W3,
                     ushort16* __restrict__ xbf, ushort16* __restrict__ Wbf,
                     int* __restrict__ gbucket) {
    const int i = blockIdx.x * blockDim.x + threadIdx.x;
    if (i < NN * D) xbf[i] = f2bf(x0[i]);
    if (i < D * D) {
        Wbf[i] = f2bf(W1[i]);
        Wbf[i + D * D] = f2bf(W2[i]);
        Wbf[i + 2 * D * D] = f2bf(W3[i]);
    }
    if (i < 256) gbucket[i] = 0;
}

// ---- CSR build -----------------------------------------------------------

// coarse histogram over 196 buckets (dst>>8)
__global__ __launch_bounds__(256) void coarse_hist(const int* __restrict__ dst,
                                                   int* __restrict__ gbucket) {
    __shared__ int hcnt[256];
    const int t = threadIdx.x;
    hcnt[t] = 0;
    __syncthreads();
    const int e0 = blockIdx.x * 8192;
    const int e1 = (e0 + 8192 < EE) ? e0 + 8192 : EE;
    for (int s = e0 + t; s < e1; s += 256) atomicAdd(&hcnt[dst[s] >> 8], 1);
    __syncthreads();
    if (t < NB && hcnt[t]) atomicAdd(&gbucket[t], hcnt[t]);
}

// single tiny block: scan 196 bucket sums -> bstart, init bcursor, rowptr[NN]
__global__ void coarse_scan(const int* __restrict__ gbucket, int* __restrict__ bstart,
                            int* __restrict__ bcursor, int* __restrict__ rowptr) {
    __shared__ int s[256];
    const int t = threadIdx.x;
    const int v = (t < NB) ? gbucket[t] : 0;
    s[t] = v;
    __syncthreads();
    for (int off = 1; off < 256; off <<= 1) {
        const int add = (t >= off) ? s[t - off] : 0;
        __syncthreads();
        s[t] += add;
        __syncthreads();
    }
    const int excl = s[t] - v;
    if (t < NB) {
        bstart[t] = excl;
        bcursor[t * 16] = excl;
    }
    if (t == NB - 1) bstart[NB] = excl + v;  // == EE
    if (t == 0) rowptr[NN] = EE;
}

// pass 1: per-WG LDS hist over coarse buckets, reserve slabs, write packed
__global__ __launch_bounds__(256) void fill_coarse(const int* __restrict__ src,
                                                   const int* __restrict__ dst,
                                                   int* __restrict__ bcursor,
                                                   int* __restrict__ espacked) {
    __shared__ int hcnt[256];
    __shared__ int hbase[256];
    const int t = threadIdx.x;
    const int e0 = blockIdx.x * CHUNK;
    const int e1 = (e0 + CHUNK < EE) ? e0 + CHUNK : EE;
    hcnt[t] = 0;
    __syncthreads();
    for (int s = e0 + t; s < e1; s += 256) atomicAdd(&hcnt[dst[s] >> 8], 1);
    __syncthreads();
    if (t < NB) {
        const int c = hcnt[t];
        hbase[t] = c ? atomicAdd(&bcursor[t * 16], c) : 0;
    }
    hcnt[t] = 0;
    __syncthreads();
    for (int s = e0 + t; s < e1; s += 256) {
        const int d = dst[s];
        const int b = d >> 8;
        const int r = atomicAdd(&hcnt[b], 1);
        espacked[hbase[b] + r] = (src[s] << 8) | (d & 255);
    }
}

// pass 2: per bucket: LDS count -> LDS scan -> rowptr -> LDS-cursor scatter
__global__ __launch_bounds__(256) void bucket_scatter(const int* __restrict__ espacked,
                                                      const int* __restrict__ bstart,
                                                      int* __restrict__ rowptr,
                                                      int* __restrict__ esrc) {
    __shared__ int cnt[256];
    __shared__ int sc[256];
    __shared__ int cur[256];
    const int b = blockIdx.x;
    const int t = threadIdx.x;
    const int n0 = b * 256;
    const int seg0 = bstart[b];
    const int seg1 = bstart[b + 1];
    cnt[t] = 0;
    __syncthreads();
    for (int s = seg0 + t; s < seg1; s += 256) atomicAdd(&cnt[espacked[s] & 255], 1);
    __syncthreads();
    const int v = cnt[t];
    sc[t] = v;
    __syncthreads();
    for (int off = 1; off < 256; off <<= 1) {
        const int add = (t >= off) ? sc[t - off] : 0;
        __syncthreads();
        sc[t] += add;
        __syncthreads();
    }
    const int excl = seg0 + sc[t] - v;
    if (n0 + t < NN) rowptr[n0 + t] = excl;
    cur[t] = excl;
    __syncthreads();
    for (int s = seg0 + t; s < seg1; s += 256) {
        const int p = espacked[s];
        const int pos = atomicAdd(&cur[p & 255], 1);
        esrc[pos] = p >> 8;
    }
}

// ---- MFMA linear: h[n,f] = bf16( sum_k x[n,k]*W[f,k] + b[f] ), bf16 in --

__global__ __launch_bounds__(256) void linear_mfma(const ushort16* __restrict__ x,
                                                   const ushort16* __restrict__ Wbf,
                                                   const float* __restrict__ bias,
                                                   ushort16* __restrict__ h) {
    const int wave = threadIdx.x >> 6;
    const int lane = threadIdx.x & 63;
    const int m0 = blockIdx.x * 64 + wave * 16;
    if (m0 >= NN) return;
    const int lr = lane & 15;         // A row / B col / D col
    const int lk = (lane >> 4) * 8;   // k-octet base

    f32x4 acc[8] = {};
#pragma unroll
    for (int k4 = 0; k4 < 4; ++k4) {
        const int kb = k4 * 32 + lk;
        const short8 af = *(const short8*)(x + (long long)(m0 + lr) * D + kb);
#pragma unroll
        for (int nt = 0; nt < 8; ++nt) {
            const short8 bfrag = *(const short8*)(Wbf + (nt * 16 + lr) * D + kb);
            acc[nt] = __builtin_amdgcn_mfma_f32_16x16x32_bf16(af, bfrag, acc[nt], 0, 0, 0);
        }
    }
    const int rbase = m0 + (lane >> 4) * 4;
#pragma unroll
    for (int nt = 0; nt < 8; ++nt) {
        const int f = nt * 16 + lr;
        const float bb = bias[f];
#pragma unroll
        for (int r = 0; r < 4; ++r)
            h[(long long)(rbase + r) * D + f] = f2bf(acc[nt][r] + bb);
    }
}

// ---- aggregate: MODE 0 -> bf16 out; MODE 1 -> fp32 out + fused head -----

template <int MODE>
__global__ __launch_bounds__(256) void gin_aggregate_bf16(const uint32* __restrict__ h,
                                                          const int* __restrict__ rowptr,
                                                          const int* __restrict__ esrc,
                                                          void* __restrict__ outv,
                                                          const float* __restrict__ Wout,
                                                          const float* __restrict__ bout,
                                                          float* __restrict__ logits,
                                                          float* __restrict__ ypred) {
    const int wave = threadIdx.x >> 6;
    const int lane = threadIdx.x & 63;
    const int node = __builtin_amdgcn_readfirstlane(blockIdx.x * 4 + wave);
    if (node >= NN) return;
    const int beg = rowptr[node];
    const int end = rowptr[node + 1];
    uint32 p = h[(long long)node * (D / 2) + lane];
    float acc0 = bflo(p), acc1 = bfhi(p);
    int i = beg;
    for (; i + 8 <= end; i += 8) {
        const int s0 = esrc[i + 0], s1 = esrc[i + 1], s2 = esrc[i + 2], s3 = esrc[i + 3];
        const int s4 = esrc[i + 4], s5 = esrc[i + 5], s6 = esrc[i + 6], s7 = esrc[i + 7];
        const uint32 p0 = h[(long long)s0 * (D / 2) + lane];
        const uint32 p1 = h[(long long)s1 * (D / 2) + lane];
        const uint32 p2 = h[(long long)s2 * (D / 2) + lane];
        const uint32 p3 = h[(long long)s3 * (D / 2) + lane];
        const uint32 p4 = h[(long long)s4 * (D / 2) + lane];
        const uint32 p5 = h[(long long)s5 * (D / 2) + lane];
        const uint32 p6 = h[(long long)s6 * (D / 2) + lane];
        const uint32 p7 = h[(long long)s7 * (D / 2) + lane];
        acc0 += ((bflo(p0) + bflo(p1)) + (bflo(p2) + bflo(p3))) +
                ((bflo(p4) + bflo(p5)) + (bflo(p6) + bflo(p7)));
        acc1 += ((bfhi(p0) + bfhi(p1)) + (bfhi(p2) + bfhi(p3))) +
                ((bfhi(p4) + bfhi(p5)) + (bfhi(p6) + bfhi(p7)));
    }
    for (; i < end; ++i) {
        const uint32 q = h[(long long)esrc[i] * (D / 2) + lane];
        acc0 += bflo(q);
        acc1 += bfhi(q);
    }
    const float r0 = fmaxf(acc0, 0.f);
    const float r1 = fmaxf(acc1, 0.f);

    if (MODE == 0) {
        // pack to bf16: low ushort = even feat (2*lane), high = odd
        ((uint32*)outv)[(long long)node * (D / 2) + lane] =
            ((uint32)f2bf(r1) << 16) | (uint32)f2bf(r0);
    } else {
        float2 r;
        r.x = r0;
        r.y = r1;
        ((float2*)((float*)outv + (long long)node * D))[lane] = r;
        const float2 w0 = ((const float2*)(Wout + 0 * D))[lane];
        const float2 w1 = ((const float2*)(Wout + 1 * D))[lane];
        const float2 w2 = ((const float2*)(Wout + 2 * D))[lane];
        float l0 = r0 * w0.x + r1 * w0.y;
        float l1 = r0 * w1.x + r1 * w1.y;
        float l2 = r0 * w2.x + r1 * w2.y;
#pragma unroll
        for (int off = 32; off > 0; off >>= 1) {
            l0 += __shfl_xor(l0, off, 64);
            l1 += __shfl_xor(l1, off, 64);
            l2 += __shfl_xor(l2, off, 64);
        }
        if (lane == 0) {
            l0 += bout[0]; l1 += bout[1]; l2 += bout[2];
            logits[node * 3 + 0] = l0;
            logits[node * 3 + 1] = l1;
            logits[node * 3 + 2] = l2;
            int best = 0;
            float bv = l0;
            if (l1 > bv) { bv = l1; best = 1; }
            if (l2 > bv) { bv = l2; best = 2; }
            ypred[node] = (float)best;
        }
    }
}

__global__ void gather_out(const float* __restrict__ logits, const float* __restrict__ ypred,
                           const int* __restrict__ nidx, float* __restrict__ node_out,
                           float* __restrict__ y_nodepred) {
    const int m = blockIdx.x * blockDim.x + threadIdx.x;
    if (m >= MIDX) return;
    const int n = nidx[m];
    node_out[m * 3 + 0] = logits[n * 3 + 0];
    node_out[m * 3 + 1] = logits[n * 3 + 1];
    node_out[m * 3 + 2] = logits[n * 3 + 2];
    y_nodepred[m] = ypred[n];
}

extern "C" void kernel_launch(void* const* d_in, const int* in_sizes, int n_in,
                              void* d_out, int out_size, void* d_ws, size_t ws_size,
                              hipStream_t stream) {
    const float* x0 = (const float*)d_in[0];
    const int* ei = (const int*)d_in[1];
    const int* src = ei;        // edge_index[0]
    const int* dst = ei + EE;   // edge_index[1]
    const int* nidx = (const int*)d_in[3];
    const float* W1 = (const float*)d_in[4];
    const float* b1 = (const float*)d_in[5];
    const float* W2 = (const float*)d_in[6];
    const float* b2 = (const float*)d_in[7];
    const float* W3 = (const float*)d_in[8];
    const float* b3 = (const float*)d_in[9];
    const float* Wout = (const float*)d_in[10];
    const float* bout = (const float*)d_in[11];

    char* ws = (char*)d_ws;
    ushort16* xbf  = (ushort16*)ws;                                // N*D bf16 (x0 conv)
    ushort16* hbuf = xbf + (long long)NN * D;                      // N*D bf16
    ushort16* xbuf = hbuf + (long long)NN * D;                     // N*D bf16 (inter-layer)
    ushort16* Wbf  = xbuf + (long long)NN * D;                     // 3*D*D bf16
    float* logits  = (float*)(Wbf + 3 * D * D);                    // N*3
    int* rowptr    = (int*)(logits + (long long)NN * NCLS);        // NN+1
    int* gbucket   = rowptr + NN + 4;                              // 256
    int* bstart    = gbucket + 256;                                // NB+1 (pad 256)
    int* bcursor   = bstart + 256;                                 // NB*16
    int* espacked  = bcursor + NB * 16 + 12;                       // EE
    int* esrc      = espacked + EE;                                // EE

    float* out = (float*)d_out;
    float* xe       = out;                       // N*D
    float* node_out = out + (long long)NN * D;   // M*3
    float* yp       = node_out + MIDX * NCLS;    // N
    float* ynp      = yp + NN;                   // M

    // ---- prep + CSR build ----
    prep<<<(NN * D + 255) / 256, 256, 0, stream>>>(x0, W1, W2, W3, xbf, Wbf, gbucket);
    coarse_hist<<<(EE + 8191) / 8192, 256, 0, stream>>>(dst, gbucket);
    coarse_scan<<<1, 256, 0, stream>>>(gbucket, bstart, bcursor, rowptr);
    fill_coarse<<<(EE + CHUNK - 1) / CHUNK, 256, 0, stream>>>(src, dst, bcursor, espacked);
    bucket_scatter<<<NB, 256, 0, stream>>>(espacked, bstart, rowptr, esrc);

    // ---- 3 GIN layers ----
    const int lin_blocks = (NN + 63) / 64;
    const int agg_blocks = (NN + 3) / 4;
    linear_mfma<<<lin_blocks, 256, 0, stream>>>(xbf, Wbf, b1, hbuf);
    gin_aggregate_bf16<0><<<agg_blocks, 256, 0, stream>>>((const uint32*)hbuf, rowptr, esrc,
                                                          xbuf, nullptr, nullptr, nullptr, nullptr);
    linear_mfma<<<lin_blocks, 256, 0, stream>>>(xbuf, Wbf + (long long)D * D, b2, hbuf);
    gin_aggregate_bf16<0><<<agg_blocks, 256, 0, stream>>>((const uint32*)hbuf, rowptr, esrc,
                                                          xbuf, nullptr, nullptr, nullptr, nullptr);
    linear_mfma<<<lin_blocks, 256, 0, stream>>>(xbuf, Wbf + 2LL * D * D, b3, hbuf);
    gin_aggregate_bf16<1><<<agg_blocks, 256, 0, stream>>>((const uint32*)hbuf, rowptr, esrc,
                                                          xe, Wout, bout, logits, yp);

    gather_out<<<(MIDX + 255) / 256, 256, 0, stream>>>(logits, yp, nidx, node_out, ynp);
}

// Round 7
// 201.719 us; speedup vs baseline: 25.5871x; 1.1202x over previous
//
#include <hip/hip_runtime.h>

#define NN 50000
#define EE 800000
#define D 128
#define NCLS 3
#define MIDX 10000
#define NB 196           // coarse buckets = ceil(NN/256)
#define CHUNK 4096       // edges per WG in fill_coarse
#define HIST_WGS 98      // 98 * 8192 >= EE
#define CONV_WGS 25000   // NN*D/256

typedef unsigned int uint32;
typedef unsigned short ushort16;
typedef __attribute__((ext_vector_type(8))) short short8;
typedef __attribute__((ext_vector_type(4))) float f32x4;

__device__ __forceinline__ ushort16 f2bf(float f) {
    uint32 u = __float_as_uint(f);
    u = (u + 0x7fffu + ((u >> 16) & 1u)) >> 16;  // round-to-nearest-even
    return (ushort16)u;
}
__device__ __forceinline__ float bflo(uint32 packed) {
    return __uint_as_float(packed << 16);
}
__device__ __forceinline__ float bfhi(uint32 packed) {
    return __uint_as_float(packed & 0xFFFF0000u);
}

// ---- prep (x0,W -> bf16) + coarse hist, one kernel ----------------------

__global__ __launch_bounds__(256) void prep_hist(const float* __restrict__ x0,
                                                 const float* __restrict__ W1,
                                                 const float* __restrict__ W2,
                                                 const float* __restrict__ W3,
                                                 const int* __restrict__ dst,
                                                 ushort16* __restrict__ xbf,
                                                 ushort16* __restrict__ Wbf,
                                                 int* __restrict__ hpart) {
    const int t = threadIdx.x;
    if (blockIdx.x < CONV_WGS) {
        const int i = blockIdx.x * 256 + t;
        xbf[i] = f2bf(x0[i]);
        if (i < D * D) {
            Wbf[i] = f2bf(W1[i]);
            Wbf[i + D * D] = f2bf(W2[i]);
            Wbf[i + 2 * D * D] = f2bf(W3[i]);
        }
    } else {
        __shared__ int hcnt[256];
        const int b = blockIdx.x - CONV_WGS;
        hcnt[t] = 0;
        __syncthreads();
        const int e0 = b * 8192;
        const int e1 = (e0 + 8192 < EE) ? e0 + 8192 : EE;
        for (int s = e0 + t; s < e1; s += 256) atomicAdd(&hcnt[dst[s] >> 8], 1);
        __syncthreads();
        hpart[b * 256 + t] = hcnt[t];  // fully written each call; no init needed
    }
}

// single tiny block: sum partials, scan -> bstart, bcursor, rowptr[NN]
__global__ void coarse_scan(const int* __restrict__ hpart, int* __restrict__ bstart,
                            int* __restrict__ bcursor, int* __restrict__ rowptr) {
    __shared__ int s[256];
    const int t = threadIdx.x;
    int v = 0;
    if (t < NB)
        for (int w = 0; w < HIST_WGS; ++w) v += hpart[w * 256 + t];
    s[t] = v;
    __syncthreads();
    for (int off = 1; off < 256; off <<= 1) {
        const int add = (t >= off) ? s[t - off] : 0;
        __syncthreads();
        s[t] += add;
        __syncthreads();
    }
    const int excl = s[t] - v;
    if (t < NB) {
        bstart[t] = excl;
        bcursor[t * 16] = excl;
    }
    if (t == NB - 1) bstart[NB] = excl + v;  // == EE
    if (t == 0) rowptr[NN] = EE;
}

// pass 1: per-WG LDS hist over coarse buckets, reserve slabs, write packed
__global__ __launch_bounds__(256) void fill_coarse(const int* __restrict__ src,
                                                   const int* __restrict__ dst,
                                                   int* __restrict__ bcursor,
                                                   int* __restrict__ espacked) {
    __shared__ int hcnt[256];
    __shared__ int hbase[256];
    const int t = threadIdx.x;
    const int e0 = blockIdx.x * CHUNK;
    const int e1 = (e0 + CHUNK < EE) ? e0 + CHUNK : EE;
    hcnt[t] = 0;
    __syncthreads();
    for (int s = e0 + t; s < e1; s += 256) atomicAdd(&hcnt[dst[s] >> 8], 1);
    __syncthreads();
    if (t < NB) {
        const int c = hcnt[t];
        hbase[t] = c ? atomicAdd(&bcursor[t * 16], c) : 0;
    }
    hcnt[t] = 0;
    __syncthreads();
    for (int s = e0 + t; s < e1; s += 256) {
        const int d = dst[s];
        const int b = d >> 8;
        const int r = atomicAdd(&hcnt[b], 1);
        espacked[hbase[b] + r] = (src[s] << 8) | (d & 255);
    }
}

// pass 2: per bucket: LDS count -> scan -> rowptr -> LDS-cursor scatter
__global__ __launch_bounds__(256) void bucket_scatter(const int* __restrict__ espacked,
                                                      const int* __restrict__ bstart,
                                                      int* __restrict__ rowptr,
                                                      int* __restrict__ esrc) {
    __shared__ int cnt[256];
    __shared__ int sc[256];
    __shared__ int cur[256];
    const int b = blockIdx.x;
    const int t = threadIdx.x;
    const int n0 = b * 256;
    const int seg0 = bstart[b];
    const int seg1 = bstart[b + 1];
    cnt[t] = 0;
    __syncthreads();
    for (int s = seg0 + t; s < seg1; s += 256) atomicAdd(&cnt[espacked[s] & 255], 1);
    __syncthreads();
    const int v = cnt[t];
    sc[t] = v;
    __syncthreads();
    for (int off = 1; off < 256; off <<= 1) {
        const int add = (t >= off) ? sc[t - off] : 0;
        __syncthreads();
        sc[t] += add;
        __syncthreads();
    }
    const int excl = seg0 + sc[t] - v;
    if (n0 + t < NN) rowptr[n0 + t] = excl;
    cur[t] = excl;
    __syncthreads();
    for (int s = seg0 + t; s < seg1; s += 256) {
        const int p = espacked[s];
        const int pos = atomicAdd(&cur[p & 255], 1);
        esrc[pos] = p >> 8;
    }
}

// ---- standalone MFMA linear (layer 1): h[n,f] = bf16(x@W^T + b) ---------

__global__ __launch_bounds__(256) void linear_mfma(const ushort16* __restrict__ x,
                                                   const ushort16* __restrict__ Wbf,
                                                   const float* __restrict__ bias,
                                                   ushort16* __restrict__ h) {
    const int wave = threadIdx.x >> 6;
    const int lane = threadIdx.x & 63;
    const int m0 = blockIdx.x * 64 + wave * 16;
    if (m0 >= NN) return;
    const int lr = lane & 15;
    const int lk = (lane >> 4) * 8;

    f32x4 acc[8] = {};
#pragma unroll
    for (int k4 = 0; k4 < 4; ++k4) {
        const int kb = k4 * 32 + lk;
        const short8 af = *(const short8*)(x + (long long)(m0 + lr) * D + kb);
#pragma unroll
        for (int nt = 0; nt < 8; ++nt) {
            const short8 bfrag = *(const short8*)(Wbf + (nt * 16 + lr) * D + kb);
            acc[nt] = __builtin_amdgcn_mfma_f32_16x16x32_bf16(af, bfrag, acc[nt], 0, 0, 0);
        }
    }
    const int rbase = m0 + (lane >> 4) * 4;
#pragma unroll
    for (int nt = 0; nt < 8; ++nt) {
        const int f = nt * 16 + lr;
        const float bb = bias[f];
#pragma unroll
        for (int r = 0; r < 4; ++r)
            h[(long long)(rbase + r) * D + f] = f2bf(acc[nt][r] + bb);
    }
}

// ---- FUSED: aggregate(h) -> relu -> LDS tile -> MFMA next linear --------
// block = 16 nodes; 4 waves aggregate 4 nodes each, then MFMA 2 f-tiles each.

__global__ __launch_bounds__(256) void agg_linear(const uint32* __restrict__ h,
                                                  const int* __restrict__ rowptr,
                                                  const int* __restrict__ esrc,
                                                  const ushort16* __restrict__ Wbf,
                                                  const float* __restrict__ bias,
                                                  ushort16* __restrict__ hnext) {
    __shared__ uint32 xs[16][68];  // 16 rows x 64 used words, +4 pad (bank spread)
    const int wave = threadIdx.x >> 6;
    const int lane = threadIdx.x & 63;
    const int m0 = blockIdx.x * 16;

#pragma unroll
    for (int j = 0; j < 4; ++j) {
        const int row = wave * 4 + j;
        const int node = __builtin_amdgcn_readfirstlane(m0 + row);
        const int beg = rowptr[node];
        const int end = rowptr[node + 1];
        const uint32 p = h[(long long)node * (D / 2) + lane];
        float acc0 = bflo(p), acc1 = bfhi(p);
        int i = beg;
        for (; i + 8 <= end; i += 8) {
            const int s0 = esrc[i + 0], s1 = esrc[i + 1], s2 = esrc[i + 2], s3 = esrc[i + 3];
            const int s4 = esrc[i + 4], s5 = esrc[i + 5], s6 = esrc[i + 6], s7 = esrc[i + 7];
            const uint32 p0 = h[(long long)s0 * (D / 2) + lane];
            const uint32 p1 = h[(long long)s1 * (D / 2) + lane];
            const uint32 p2 = h[(long long)s2 * (D / 2) + lane];
            const uint32 p3 = h[(long long)s3 * (D / 2) + lane];
            const uint32 p4 = h[(long long)s4 * (D / 2) + lane];
            const uint32 p5 = h[(long long)s5 * (D / 2) + lane];
            const uint32 p6 = h[(long long)s6 * (D / 2) + lane];
            const uint32 p7 = h[(long long)s7 * (D / 2) + lane];
            acc0 += ((bflo(p0) + bflo(p1)) + (bflo(p2) + bflo(p3))) +
                    ((bflo(p4) + bflo(p5)) + (bflo(p6) + bflo(p7)));
            acc1 += ((bfhi(p0) + bfhi(p1)) + (bfhi(p2) + bfhi(p3))) +
                    ((bfhi(p4) + bfhi(p5)) + (bfhi(p6) + bfhi(p7)));
        }
        for (; i < end; ++i) {
            const uint32 q = h[(long long)esrc[i] * (D / 2) + lane];
            acc0 += bflo(q);
            acc1 += bfhi(q);
        }
        xs[row][lane] = ((uint32)f2bf(fmaxf(acc1, 0.f)) << 16) |
                        (uint32)f2bf(fmaxf(acc0, 0.f));
    }
    __syncthreads();

    const int lr = lane & 15;
    const int lk = (lane >> 4) * 8;
    f32x4 acc[2] = {};
#pragma unroll
    for (int k4 = 0; k4 < 4; ++k4) {
        const int kb = k4 * 32 + lk;
        const short8 af = *(const short8*)&xs[lr][kb >> 1];
#pragma unroll
        for (int f = 0; f < 2; ++f) {
            const int ft = wave * 2 + f;
            const short8 bfrag = *(const short8*)(Wbf + (ft * 16 + lr) * D + kb);
            acc[f] = __builtin_amdgcn_mfma_f32_16x16x32_bf16(af, bfrag, acc[f], 0, 0, 0);
        }
    }
    const int rbase = m0 + (lane >> 4) * 4;
#pragma unroll
    for (int f = 0; f < 2; ++f) {
        const int col = (wave * 2 + f) * 16 + lr;
        const float bb = bias[col];
#pragma unroll
        for (int r = 0; r < 4; ++r)
            hnext[(long long)(rbase + r) * D + col] = f2bf(acc[f][r] + bb);
    }
}

// ---- last layer: aggregate -> fp32 xe + fused head ----------------------

__global__ __launch_bounds__(256) void agg_head(const uint32* __restrict__ h,
                                                const int* __restrict__ rowptr,
                                                const int* __restrict__ esrc,
                                                float* __restrict__ xe,
                                                const float* __restrict__ Wout,
                                                const float* __restrict__ bout,
                                                float* __restrict__ logits,
                                                float* __restrict__ ypred) {
    const int wave = threadIdx.x >> 6;
    const int lane = threadIdx.x & 63;
    const int node = __builtin_amdgcn_readfirstlane(blockIdx.x * 4 + wave);
    if (node >= NN) return;
    const int beg = rowptr[node];
    const int end = rowptr[node + 1];
    const uint32 p = h[(long long)node * (D / 2) + lane];
    float acc0 = bflo(p), acc1 = bfhi(p);
    int i = beg;
    for (; i + 8 <= end; i += 8) {
        const int s0 = esrc[i + 0], s1 = esrc[i + 1], s2 = esrc[i + 2], s3 = esrc[i + 3];
        const int s4 = esrc[i + 4], s5 = esrc[i + 5], s6 = esrc[i + 6], s7 = esrc[i + 7];
        const uint32 p0 = h[(long long)s0 * (D / 2) + lane];
        const uint32 p1 = h[(long long)s1 * (D / 2) + lane];
        const uint32 p2 = h[(long long)s2 * (D / 2) + lane];
        const uint32 p3 = h[(long long)s3 * (D / 2) + lane];
        const uint32 p4 = h[(long long)s4 * (D / 2) + lane];
        const uint32 p5 = h[(long long)s5 * (D / 2) + lane];
        const uint32 p6 = h[(long long)s6 * (D / 2) + lane];
        const uint32 p7 = h[(long long)s7 * (D / 2) + lane];
        acc0 += ((bflo(p0) + bflo(p1)) + (bflo(p2) + bflo(p3))) +
                ((bflo(p4) + bflo(p5)) + (bflo(p6) + bflo(p7)));
        acc1 += ((bfhi(p0) + bfhi(p1)) + (bfhi(p2) + bfhi(p3))) +
                ((bfhi(p4) + bfhi(p5)) + (bfhi(p6) + bfhi(p7)));
    }
    for (; i < end; ++i) {
        const uint32 q = h[(long long)esrc[i] * (D / 2) + lane];
        acc0 += bflo(q);
        acc1 += bfhi(q);
    }
    const float r0 = fmaxf(acc0, 0.f);
    const float r1 = fmaxf(acc1, 0.f);
    float2 r;
    r.x = r0;
    r.y = r1;
    ((float2*)(xe + (long long)node * D))[lane] = r;

    const float2 w0 = ((const float2*)(Wout + 0 * D))[lane];
    const float2 w1 = ((const float2*)(Wout + 1 * D))[lane];
    const float2 w2 = ((const float2*)(Wout + 2 * D))[lane];
    float l0 = r0 * w0.x + r1 * w0.y;
    float l1 = r0 * w1.x + r1 * w1.y;
    float l2 = r0 * w2.x + r1 * w2.y;
#pragma unroll
    for (int off = 32; off > 0; off >>= 1) {
        l0 += __shfl_xor(l0, off, 64);
        l1 += __shfl_xor(l1, off, 64);
        l2 += __shfl_xor(l2, off, 64);
    }
    if (lane == 0) {
        l0 += bout[0]; l1 += bout[1]; l2 += bout[2];
        logits[node * 3 + 0] = l0;
        logits[node * 3 + 1] = l1;
        logits[node * 3 + 2] = l2;
        int best = 0;
        float bv = l0;
        if (l1 > bv) { bv = l1; best = 1; }
        if (l2 > bv) { bv = l2; best = 2; }
        ypred[node] = (float)best;
    }
}

__global__ void gather_out(const float* __restrict__ logits, const float* __restrict__ ypred,
                           const int* __restrict__ nidx, float* __restrict__ node_out,
                           float* __restrict__ y_nodepred) {
    const int m = blockIdx.x * blockDim.x + threadIdx.x;
    if (m >= MIDX) return;
    const int n = nidx[m];
    node_out[m * 3 + 0] = logits[n * 3 + 0];
    node_out[m * 3 + 1] = logits[n * 3 + 1];
    node_out[m * 3 + 2] = logits[n * 3 + 2];
    y_nodepred[m] = ypred[n];
}

extern "C" void kernel_launch(void* const* d_in, const int* in_sizes, int n_in,
                              void* d_out, int out_size, void* d_ws, size_t ws_size,
                              hipStream_t stream) {
    const float* x0 = (const float*)d_in[0];
    const int* ei = (const int*)d_in[1];
    const int* src = ei;        // edge_index[0]
    const int* dst = ei + EE;   // edge_index[1]
    const int* nidx = (const int*)d_in[3];
    const float* W1 = (const float*)d_in[4];
    const float* b1 = (const float*)d_in[5];
    const float* W2 = (const float*)d_in[6];
    const float* b2 = (const float*)d_in[7];
    const float* W3 = (const float*)d_in[8];
    const float* b3 = (const float*)d_in[9];
    const float* Wout = (const float*)d_in[10];
    const float* bout = (const float*)d_in[11];

    char* ws = (char*)d_ws;
    ushort16* xbf  = (ushort16*)ws;                                // N*D bf16  (buffer A)
    ushort16* hbuf = xbf + (long long)NN * D;                      // N*D bf16  (buffer B)
    ushort16* Wbf  = hbuf + (long long)NN * D;                     // 3*D*D bf16
    float* logits  = (float*)(Wbf + 3 * D * D);                    // N*3
    int* rowptr    = (int*)(logits + (long long)NN * NCLS);        // NN+1 (+pad)
    int* hpart     = rowptr + NN + 4;                              // HIST_WGS*256
    int* bstart    = hpart + HIST_WGS * 256;                       // NB+1 (pad 256)
    int* bcursor   = bstart + 256;                                 // NB*16
    int* espacked  = bcursor + NB * 16 + 12;                       // EE
    int* esrc      = espacked + EE;                                // EE

    float* out = (float*)d_out;
    float* xe       = out;                       // N*D
    float* node_out = out + (long long)NN * D;   // M*3
    float* yp       = node_out + MIDX * NCLS;    // N
    float* ynp      = yp + NN;                   // M

    // ---- prep + CSR build ----
    prep_hist<<<CONV_WGS + HIST_WGS, 256, 0, stream>>>(x0, W1, W2, W3, dst, xbf, Wbf, hpart);
    coarse_scan<<<1, 256, 0, stream>>>(hpart, bstart, bcursor, rowptr);
    fill_coarse<<<(EE + CHUNK - 1) / CHUNK, 256, 0, stream>>>(src, dst, bcursor, espacked);
    bucket_scatter<<<NB, 256, 0, stream>>>(espacked, bstart, rowptr, esrc);

    // ---- 3 GIN layers (linear1, then fused agg+linear x2, then agg+head) ----
    linear_mfma<<<(NN + 63) / 64, 256, 0, stream>>>(xbf, Wbf, b1, hbuf);                 // A->B (h1)
    agg_linear<<<NN / 16, 256, 0, stream>>>((const uint32*)hbuf, rowptr, esrc,
                                            Wbf + (long long)D * D, b2, xbf);            // B->A (h2)
    agg_linear<<<NN / 16, 256, 0, stream>>>((const uint32*)xbf, rowptr, esrc,
                                            Wbf + 2LL * D * D, b3, hbuf);                // A->B (h3)
    agg_head<<<(NN + 3) / 4, 256, 0, stream>>>((const uint32*)hbuf, rowptr, esrc,
                                               xe, Wout, bout, logits, yp);
    gather_out<<<(MIDX + 255) / 256, 256, 0, stream>>>(logits, yp, nidx, node_out, ynp);
}

// Round 8
// 193.197 us; speedup vs baseline: 26.7158x; 1.0441x over previous
//
#include <hip/hip_runtime.h>

#define NN 50000
#define EE 800000
#define D 128
#define NCLS 3
#define MIDX 10000
#define NB 196           // coarse buckets = ceil(NN/256)
#define CHUNK 4096       // edges per WG in fill_coarse
#define HIST_WGS 98      // 98 * 8192 >= EE
#define CONV_WGS 25000   // NN*D/256

typedef unsigned int uint32;
typedef unsigned short ushort16;
typedef __attribute__((ext_vector_type(8))) short short8;
typedef __attribute__((ext_vector_type(4))) float f32x4;

__device__ __forceinline__ ushort16 f2bf(float f) {
    uint32 u = __float_as_uint(f);
    u = (u + 0x7fffu + ((u >> 16) & 1u)) >> 16;  // round-to-nearest-even
    return (ushort16)u;
}
__device__ __forceinline__ float bflo(uint32 packed) {
    return __uint_as_float(packed << 16);
}
__device__ __forceinline__ float bfhi(uint32 packed) {
    return __uint_as_float(packed & 0xFFFF0000u);
}

// deep-MLP neighbor gather: 16 outstanding row loads per batch
__device__ __forceinline__ void gather_rows(const uint32* __restrict__ h,
                                            const int* __restrict__ esrc,
                                            int beg, int end, int lane,
                                            float& a0, float& a1) {
    int i = beg;
    for (; i + 16 <= end; i += 16) {
        int s[16];
        uint32 q[16];
#pragma unroll
        for (int k = 0; k < 16; ++k) s[k] = esrc[i + k];
#pragma unroll
        for (int k = 0; k < 16; ++k) q[k] = h[(long long)s[k] * (D / 2) + lane];
        float t0a = 0.f, t0b = 0.f, t1a = 0.f, t1b = 0.f;
#pragma unroll
        for (int k = 0; k < 16; k += 2) {
            t0a += bflo(q[k]);     t1a += bfhi(q[k]);
            t0b += bflo(q[k + 1]); t1b += bfhi(q[k + 1]);
        }
        a0 += t0a + t0b;
        a1 += t1a + t1b;
    }
    for (; i + 4 <= end; i += 4) {
        int s[4];
        uint32 q[4];
#pragma unroll
        for (int k = 0; k < 4; ++k) s[k] = esrc[i + k];
#pragma unroll
        for (int k = 0; k < 4; ++k) q[k] = h[(long long)s[k] * (D / 2) + lane];
        a0 += (bflo(q[0]) + bflo(q[1])) + (bflo(q[2]) + bflo(q[3]));
        a1 += (bfhi(q[0]) + bfhi(q[1])) + (bfhi(q[2]) + bfhi(q[3]));
    }
    for (; i < end; ++i) {
        const uint32 q = h[(long long)esrc[i] * (D / 2) + lane];
        a0 += bflo(q);
        a1 += bfhi(q);
    }
}

// ---- prep (x0,W -> bf16) + coarse hist, one kernel ----------------------

__global__ __launch_bounds__(256) void prep_hist(const float* __restrict__ x0,
                                                 const float* __restrict__ W1,
                                                 const float* __restrict__ W2,
                                                 const float* __restrict__ W3,
                                                 const int* __restrict__ dst,
                                                 ushort16* __restrict__ xbf,
                                                 ushort16* __restrict__ Wbf,
                                                 int* __restrict__ hpart) {
    const int t = threadIdx.x;
    if (blockIdx.x < CONV_WGS) {
        const int i = blockIdx.x * 256 + t;
        xbf[i] = f2bf(x0[i]);
        if (i < D * D) {
            Wbf[i] = f2bf(W1[i]);
            Wbf[i + D * D] = f2bf(W2[i]);
            Wbf[i + 2 * D * D] = f2bf(W3[i]);
        }
    } else {
        __shared__ int hcnt[256];
        const int b = blockIdx.x - CONV_WGS;
        hcnt[t] = 0;
        __syncthreads();
        const int e0 = b * 8192;
        const int e1 = (e0 + 8192 < EE) ? e0 + 8192 : EE;
        for (int s = e0 + t; s < e1; s += 256) atomicAdd(&hcnt[dst[s] >> 8], 1);
        __syncthreads();
        hpart[b * 256 + t] = hcnt[t];
    }
}

// single tiny block: sum partials, scan -> bstart, bcursor, rowptr[NN]
__global__ void coarse_scan(const int* __restrict__ hpart, int* __restrict__ bstart,
                            int* __restrict__ bcursor, int* __restrict__ rowptr) {
    __shared__ int s[256];
    const int t = threadIdx.x;
    int v = 0;
    if (t < NB)
        for (int w = 0; w < HIST_WGS; ++w) v += hpart[w * 256 + t];
    s[t] = v;
    __syncthreads();
    for (int off = 1; off < 256; off <<= 1) {
        const int add = (t >= off) ? s[t - off] : 0;
        __syncthreads();
        s[t] += add;
        __syncthreads();
    }
    const int excl = s[t] - v;
    if (t < NB) {
        bstart[t] = excl;
        bcursor[t * 16] = excl;
    }
    if (t == NB - 1) bstart[NB] = excl + v;  // == EE
    if (t == 0) rowptr[NN] = EE;
}

// pass 1: per-WG LDS hist over coarse buckets, reserve slabs, write packed
__global__ __launch_bounds__(256) void fill_coarse(const int* __restrict__ src,
                                                   const int* __restrict__ dst,
                                                   int* __restrict__ bcursor,
                                                   int* __restrict__ espacked) {
    __shared__ int hcnt[256];
    __shared__ int hbase[256];
    const int t = threadIdx.x;
    const int e0 = blockIdx.x * CHUNK;
    const int e1 = (e0 + CHUNK < EE) ? e0 + CHUNK : EE;
    hcnt[t] = 0;
    __syncthreads();
    for (int s = e0 + t; s < e1; s += 256) atomicAdd(&hcnt[dst[s] >> 8], 1);
    __syncthreads();
    if (t < NB) {
        const int c = hcnt[t];
        hbase[t] = c ? atomicAdd(&bcursor[t * 16], c) : 0;
    }
    hcnt[t] = 0;
    __syncthreads();
    for (int s = e0 + t; s < e1; s += 256) {
        const int d = dst[s];
        const int b = d >> 8;
        const int r = atomicAdd(&hcnt[b], 1);
        espacked[hbase[b] + r] = (src[s] << 8) | (d & 255);
    }
}

// pass 2: per bucket: LDS count -> scan -> rowptr -> LDS-cursor scatter
__global__ __launch_bounds__(256) void bucket_scatter(const int* __restrict__ espacked,
                                                      const int* __restrict__ bstart,
                                                      int* __restrict__ rowptr,
                                                      int* __restrict__ esrc) {
    __shared__ int cnt[256];
    __shared__ int sc[256];
    __shared__ int cur[256];
    const int b = blockIdx.x;
    const int t = threadIdx.x;
    const int n0 = b * 256;
    const int seg0 = bstart[b];
    const int seg1 = bstart[b + 1];
    cnt[t] = 0;
    __syncthreads();
    for (int s = seg0 + t; s < seg1; s += 256) atomicAdd(&cnt[espacked[s] & 255], 1);
    __syncthreads();
    const int v = cnt[t];
    sc[t] = v;
    __syncthreads();
    for (int off = 1; off < 256; off <<= 1) {
        const int add = (t >= off) ? sc[t - off] : 0;
        __syncthreads();
        sc[t] += add;
        __syncthreads();
    }
    const int excl = seg0 + sc[t] - v;
    if (n0 + t < NN) rowptr[n0 + t] = excl;
    cur[t] = excl;
    __syncthreads();
    for (int s = seg0 + t; s < seg1; s += 256) {
        const int p = espacked[s];
        const int pos = atomicAdd(&cur[p & 255], 1);
        esrc[pos] = p >> 8;
    }
}

// ---- standalone MFMA linear (layer 1): h[n,f] = bf16(x@W^T + b) ---------

__global__ __launch_bounds__(256) void linear_mfma(const ushort16* __restrict__ x,
                                                   const ushort16* __restrict__ Wbf,
                                                   const float* __restrict__ bias,
                                                   ushort16* __restrict__ h) {
    const int wave = threadIdx.x >> 6;
    const int lane = threadIdx.x & 63;
    const int m0 = blockIdx.x * 64 + wave * 16;
    if (m0 >= NN) return;
    const int lr = lane & 15;
    const int lk = (lane >> 4) * 8;

    f32x4 acc[8] = {};
#pragma unroll
    for (int k4 = 0; k4 < 4; ++k4) {
        const int kb = k4 * 32 + lk;
        const short8 af = *(const short8*)(x + (long long)(m0 + lr) * D + kb);
#pragma unroll
        for (int nt = 0; nt < 8; ++nt) {
            const short8 bfrag = *(const short8*)(Wbf + (nt * 16 + lr) * D + kb);
            acc[nt] = __builtin_amdgcn_mfma_f32_16x16x32_bf16(af, bfrag, acc[nt], 0, 0, 0);
        }
    }
    const int rbase = m0 + (lane >> 4) * 4;
#pragma unroll
    for (int nt = 0; nt < 8; ++nt) {
        const int f = nt * 16 + lr;
        const float bb = bias[f];
#pragma unroll
        for (int r = 0; r < 4; ++r)
            h[(long long)(rbase + r) * D + f] = f2bf(acc[nt][r] + bb);
    }
}

// ---- FUSED: aggregate(h) -> relu -> LDS tile -> MFMA next linear --------

__global__ __launch_bounds__(256) void agg_linear(const uint32* __restrict__ h,
                                                  const int* __restrict__ rowptr,
                                                  const int* __restrict__ esrc,
                                                  const ushort16* __restrict__ Wbf,
                                                  const float* __restrict__ bias,
                                                  ushort16* __restrict__ hnext) {
    __shared__ uint32 xs[16][68];  // 16 rows x 64 used words, +4 pad
    const int wave = threadIdx.x >> 6;
    const int lane = threadIdx.x & 63;
    const int m0 = blockIdx.x * 16;

#pragma unroll
    for (int j = 0; j < 4; ++j) {
        const int row = wave * 4 + j;
        const int node = __builtin_amdgcn_readfirstlane(m0 + row);
        const int beg = rowptr[node];
        const int end = rowptr[node + 1];
        const uint32 p = h[(long long)node * (D / 2) + lane];
        float acc0 = bflo(p), acc1 = bfhi(p);
        gather_rows(h, esrc, beg, end, lane, acc0, acc1);
        xs[row][lane] = ((uint32)f2bf(fmaxf(acc1, 0.f)) << 16) |
                        (uint32)f2bf(fmaxf(acc0, 0.f));
    }
    __syncthreads();

    const int lr = lane & 15;
    const int lk = (lane >> 4) * 8;
    f32x4 acc[2] = {};
#pragma unroll
    for (int k4 = 0; k4 < 4; ++k4) {
        const int kb = k4 * 32 + lk;
        const short8 af = *(const short8*)&xs[lr][kb >> 1];
#pragma unroll
        for (int f = 0; f < 2; ++f) {
            const int ft = wave * 2 + f;
            const short8 bfrag = *(const short8*)(Wbf + (ft * 16 + lr) * D + kb);
            acc[f] = __builtin_amdgcn_mfma_f32_16x16x32_bf16(af, bfrag, acc[f], 0, 0, 0);
        }
    }
    const int rbase = m0 + (lane >> 4) * 4;
#pragma unroll
    for (int f = 0; f < 2; ++f) {
        const int col = (wave * 2 + f) * 16 + lr;
        const float bb = bias[col];
#pragma unroll
        for (int r = 0; r < 4; ++r)
            hnext[(long long)(rbase + r) * D + col] = f2bf(acc[f][r] + bb);
    }
}

// ---- last layer: aggregate -> fp32 xe + fused head ----------------------

__global__ __launch_bounds__(256) void agg_head(const uint32* __restrict__ h,
                                                const int* __restrict__ rowptr,
                                                const int* __restrict__ esrc,
                                                float* __restrict__ xe,
                                                const float* __restrict__ Wout,
                                                const float* __restrict__ bout,
                                                float* __restrict__ logits,
                                                float* __restrict__ ypred) {
    const int wave = threadIdx.x >> 6;
    const int lane = threadIdx.x & 63;
    const int node = __builtin_amdgcn_readfirstlane(blockIdx.x * 4 + wave);
    if (node >= NN) return;
    const int beg = rowptr[node];
    const int end = rowptr[node + 1];
    const uint32 p = h[(long long)node * (D / 2) + lane];
    float acc0 = bflo(p), acc1 = bfhi(p);
    gather_rows(h, esrc, beg, end, lane, acc0, acc1);
    const float r0 = fmaxf(acc0, 0.f);
    const float r1 = fmaxf(acc1, 0.f);
    float2 r;
    r.x = r0;
    r.y = r1;
    ((float2*)(xe + (long long)node * D))[lane] = r;

    const float2 w0 = ((const float2*)(Wout + 0 * D))[lane];
    const float2 w1 = ((const float2*)(Wout + 1 * D))[lane];
    const float2 w2 = ((const float2*)(Wout + 2 * D))[lane];
    float l0 = r0 * w0.x + r1 * w0.y;
    float l1 = r0 * w1.x + r1 * w1.y;
    float l2 = r0 * w2.x + r1 * w2.y;
#pragma unroll
    for (int off = 32; off > 0; off >>= 1) {
        l0 += __shfl_xor(l0, off, 64);
        l1 += __shfl_xor(l1, off, 64);
        l2 += __shfl_xor(l2, off, 64);
    }
    if (lane == 0) {
        l0 += bout[0]; l1 += bout[1]; l2 += bout[2];
        logits[node * 3 + 0] = l0;
        logits[node * 3 + 1] = l1;
        logits[node * 3 + 2] = l2;
        int best = 0;
        float bv = l0;
        if (l1 > bv) { bv = l1; best = 1; }
        if (l2 > bv) { bv = l2; best = 2; }
        ypred[node] = (float)best;
    }
}

__global__ void gather_out(const float* __restrict__ logits, const float* __restrict__ ypred,
                           const int* __restrict__ nidx, float* __restrict__ node_out,
                           float* __restrict__ y_nodepred) {
    const int m = blockIdx.x * blockDim.x + threadIdx.x;
    if (m >= MIDX) return;
    const int n = nidx[m];
    node_out[m * 3 + 0] = logits[n * 3 + 0];
    node_out[m * 3 + 1] = logits[n * 3 + 1];
    node_out[m * 3 + 2] = logits[n * 3 + 2];
    y_nodepred[m] = ypred[n];
}

extern "C" void kernel_launch(void* const* d_in, const int* in_sizes, int n_in,
                              void* d_out, int out_size, void* d_ws, size_t ws_size,
                              hipStream_t stream) {
    const float* x0 = (const float*)d_in[0];
    const int* ei = (const int*)d_in[1];
    const int* src = ei;        // edge_index[0]
    const int* dst = ei + EE;   // edge_index[1]
    const int* nidx = (const int*)d_in[3];
    const float* W1 = (const float*)d_in[4];
    const float* b1 = (const float*)d_in[5];
    const float* W2 = (const float*)d_in[6];
    const float* b2 = (const float*)d_in[7];
    const float* W3 = (const float*)d_in[8];
    const float* b3 = (const float*)d_in[9];
    const float* Wout = (const float*)d_in[10];
    const float* bout = (const float*)d_in[11];

    char* ws = (char*)d_ws;
    ushort16* xbf  = (ushort16*)ws;                                // N*D bf16  (buffer A)
    ushort16* hbuf = xbf + (long long)NN * D;                      // N*D bf16  (buffer B)
    ushort16* Wbf  = hbuf + (long long)NN * D;                     // 3*D*D bf16
    float* logits  = (float*)(Wbf + 3 * D * D);                    // N*3
    int* rowptr    = (int*)(logits + (long long)NN * NCLS);        // NN+1 (+pad)
    int* hpart     = rowptr + NN + 4;                              // HIST_WGS*256
    int* bstart    = hpart + HIST_WGS * 256;                       // NB+1 (pad 256)
    int* bcursor   = bstart + 256;                                 // NB*16
    int* espacked  = bcursor + NB * 16 + 12;                       // EE
    int* esrc      = espacked + EE;                                // EE

    float* out = (float*)d_out;
    float* xe       = out;                       // N*D
    float* node_out = out + (long long)NN * D;   // M*3
    float* yp       = node_out + MIDX * NCLS;    // N
    float* ynp      = yp + NN;                   // M

    // ---- prep + CSR build ----
    prep_hist<<<CONV_WGS + HIST_WGS, 256, 0, stream>>>(x0, W1, W2, W3, dst, xbf, Wbf, hpart);
    coarse_scan<<<1, 256, 0, stream>>>(hpart, bstart, bcursor, rowptr);
    fill_coarse<<<(EE + CHUNK - 1) / CHUNK, 256, 0, stream>>>(src, dst, bcursor, espacked);
    bucket_scatter<<<NB, 256, 0, stream>>>(espacked, bstart, rowptr, esrc);

    // ---- 3 GIN layers ----
    linear_mfma<<<(NN + 63) / 64, 256, 0, stream>>>(xbf, Wbf, b1, hbuf);                 // A->B (h1)
    agg_linear<<<NN / 16, 256, 0, stream>>>((const uint32*)hbuf, rowptr, esrc,
                                            Wbf + (long long)D * D, b2, xbf);            // B->A (h2)
    agg_linear<<<NN / 16, 256, 0, stream>>>((const uint32*)xbf, rowptr, esrc,
                                            Wbf + 2LL * D * D, b3, hbuf);                // A->B (h3)
    agg_head<<<(NN + 3) / 4, 256, 0, stream>>>((const uint32*)hbuf, rowptr, esrc,
                                               xe, Wout, bout, logits, yp);
    gather_out<<<(MIDX + 255) / 256, 256, 0, stream>>>(logits, yp, nidx, node_out, ynp);
}